// Round 8
// baseline (715.779 us; speedup 1.0000x reference)
//
#include <hip/hip_runtime.h>
#include <math.h>

// RegionalGNN: B=8192, NC=8, H=256, HD=1024, L=3.
// R8: mega-kernel k_net = input-proj + 3 fused layers + head, X lives in REGISTERS
//     (xf A-frag layout + xr C-layout) for the whole network; B-fragments read
//     per-lane direct from global (L2-resident weights); ZERO inner barriers.
//     (R7 lesson: A16(64reg)+xf+yfrag > 128-VGPR cap -> spill = +63MB HBM traffic.
//      R4-R7 lesson: barrier-paced LDS panel rings plateau ~7x above traffic floor.)

typedef short bf16x8 __attribute__((ext_vector_type(8)));
typedef float f32x4  __attribute__((ext_vector_type(4)));

__device__ __forceinline__ float bflo(unsigned int u){ return __uint_as_float(u << 16); }
__device__ __forceinline__ float bfhi(unsigned int u){ return __uint_as_float(u & 0xffff0000u); }
__device__ __forceinline__ float bfs(short s){ return __uint_as_float((unsigned int)(unsigned short)s << 16); }
__device__ __forceinline__ unsigned short f2bf(float f){
  unsigned int u = __float_as_uint(f);
  u += 0x7fffu + ((u >> 16) & 1u);          // RNE
  return (unsigned short)(u >> 16);
}
__device__ __forceinline__ void unpack8(uint4 a, float* o){
  o[0]=bflo(a.x); o[1]=bfhi(a.x); o[2]=bflo(a.y); o[3]=bfhi(a.y);
  o[4]=bflo(a.z); o[5]=bfhi(a.z); o[6]=bflo(a.w); o[7]=bfhi(a.w);
}
__device__ __forceinline__ uint4 pack8(const float* v){
  uint4 r;
  r.x = (unsigned int)f2bf(v[0]) | ((unsigned int)f2bf(v[1]) << 16);
  r.y = (unsigned int)f2bf(v[2]) | ((unsigned int)f2bf(v[3]) << 16);
  r.z = (unsigned int)f2bf(v[4]) | ((unsigned int)f2bf(v[5]) << 16);
  r.w = (unsigned int)f2bf(v[6]) | ((unsigned int)f2bf(v[7]) << 16);
  return r;
}
__device__ __forceinline__ void gload16(const void* g, void* l){
  __builtin_amdgcn_global_load_lds(
      (const __attribute__((address_space(1))) unsigned int*)g,
      (__attribute__((address_space(3))) unsigned int*)l, 16, 0, 0);
}
__device__ __forceinline__ bf16x8 shfl8(bf16x8 v, int src){
  union U { bf16x8 h; int u[4]; };
  U a, r; a.h = v;
  #pragma unroll
  for (int j = 0; j < 4; j++) r.u[j] = __shfl(a.u[j], src);
  return r.h;
}
__device__ __forceinline__ bf16x8 pk8(const float* v){
  bf16x8 r;
  #pragma unroll
  for (int j = 0; j < 8; j++) r[j] = (short)f2bf(v[j]);
  return r;
}

// ---------------- convert f32 -> bf16 (Wq, Wk, Wv) ----------------
struct CvP { const float* src[4]; short* dst[4]; int boff[5]; };
__global__ __launch_bounds__(256) void k_convert(CvP p){
  int bid = blockIdx.x, s = 0;
  while (bid >= p.boff[s+1]) s++;
  size_t e = (size_t)(bid - p.boff[s]) * 2048 + (size_t)threadIdx.x * 8;
  const float* src = p.src[s] + e;
  float4 v0 = *(const float4*)src;
  float4 v1 = *(const float4*)(src + 4);
  float v[8] = {v0.x,v0.y,v0.z,v0.w,v1.x,v1.y,v1.z,v1.w};
  *(uint4*)(p.dst[s] + e) = pack8(v);
}

// ---------------- transpose + convert (Wi, Wo x3, Wp) ----------------
struct TrP { const float* src[5]; short* dst[5]; int rows[5]; int cols[5]; int toff[6]; };
__global__ __launch_bounds__(256) void k_transpose(TrP p){
  __shared__ float tile[64][65];
  int bid = blockIdx.x, s = 0;
  while (bid >= p.toff[s+1]) s++;
  int ti = bid - p.toff[s];
  int cols = p.cols[s], rows = p.rows[s];
  int ntc = cols >> 6;
  int r0 = (ti / ntc) * 64, c0 = (ti % ntc) * 64;
  const float* src = p.src[s];
  int row = threadIdx.x >> 2, jb = (threadIdx.x & 3) * 16;
  #pragma unroll
  for (int j = 0; j < 16; j += 4){
    float4 v = *(const float4*)(src + (size_t)(r0 + row) * cols + c0 + jb + j);
    tile[row][jb+j] = v.x; tile[row][jb+j+1] = v.y; tile[row][jb+j+2] = v.z; tile[row][jb+j+3] = v.w;
  }
  __syncthreads();
  short* dst = p.dst[s];
  float tmp[16];
  #pragma unroll
  for (int j = 0; j < 16; j++) tmp[j] = tile[jb + j][row];
  #pragma unroll
  for (int j = 0; j < 16; j += 8)
    *(uint4*)(dst + (size_t)(c0 + row) * rows + r0 + jb + j) = pack8(&tmp[j]);
}

// ---------------- bias-fold vectors via bf16 row-dots ----------------
__global__ __launch_bounds__(256) void k_vecs2(
    const short* Wqb, const short* Wkb, const short* WoTb,
    const float* bq, const float* bk, const float* bv, const float* bo,
    float* cq, float* ck, float* cvo, float* c0){
  const int job = blockIdx.x, l = blockIdx.y, tid = threadIdx.x;
  __shared__ float sv[1024];
  __shared__ float red[256];
  if (job == 3){
    float pp = 0.f;
    #pragma unroll
    for (int i = 0; i < 4; i++){
      int d = tid*4 + i;
      pp = fmaf(bq[l*1024 + d], bk[l*1024 + d], pp);
    }
    red[tid] = pp; __syncthreads();
    for (int o = 128; o > 0; o >>= 1){ if (tid < o) red[tid] += red[tid + o]; __syncthreads(); }
    if (tid == 0) c0[l] = red[0] * 0.0625f;
    return;
  }
  const short* rows = (job==0 ? Wqb : job==1 ? Wkb : WoTb) + (size_t)l*262144;
  const float* vecg = (job==0 ? bk : job==1 ? bq : bv) + l*1024;
  const float scale = (job == 2) ? 1.0f : 0.0625f;
  for (int i = tid; i < 1024; i += 256) sv[i] = vecg[i];
  __syncthreads();
  const int row = tid >> 3, sub = tid & 7;
  for (int pass = 0; pass < 8; pass++){
    int r = pass*32 + row;
    const short* rp = rows + (size_t)r*1024;
    float acc = 0.f;
    #pragma unroll
    for (int i = 0; i < 16; i++){
      int d = sub*8 + i*64;
      uint4 v = *(const uint4*)(rp + d);
      float f[8]; unpack8(v, f);
      #pragma unroll
      for (int j = 0; j < 8; j++) acc = fmaf(f[j], sv[d + j], acc);
    }
    acc += __shfl_xor(acc, 1); acc += __shfl_xor(acc, 2); acc += __shfl_xor(acc, 4);
    if (sub == 0){
      float o = acc * scale;
      if (job == 2) o += bo[l*256 + r];
      (job==0 ? cq : job==1 ? ck : cvo)[l*256 + r] = o;
    }
  }
}

// ---------------- 128x128 MFMA GEMM (weight precompute only) ----------------
struct GDesc { const short* A; const short* Bt; short* C; int K; float scale; };
struct GemmP { GDesc d[6]; };
__global__ __launch_bounds__(256) void k_gemm128(GemmP p){
  GDesc g = p.d[blockIdx.z];
  const int tid = threadIdx.x, lane = tid & 63, w = tid >> 6;
  const int wm = w >> 1, wn = w & 1;
  __shared__ alignas(16) short As[128*32];
  __shared__ alignas(16) short Bs[128*32];
  const int K = g.K;
  const short* Ab = g.A + (size_t)blockIdx.x * 128 * K;
  const short* Bb = g.Bt + (size_t)blockIdx.y * 128 * K;
  f32x4 acc[4][4] = {};
  for (int k0 = 0; k0 < K; k0 += 32){
    #pragma unroll
    for (int i = 0; i < 2; i++){
      int s = w*2 + i;
      int ro = (s >> 2)*64 + (s & 3)*16 + (lane & 15);
      int co = k0 + (lane >> 4) * 8;
      gload16(Ab + (size_t)ro * K + co, &As[s*512]);
      gload16(Bb + (size_t)ro * K + co, &Bs[s*512]);
    }
    __syncthreads();
    bf16x8 av[4], bv[4];
    #pragma unroll
    for (int mi = 0; mi < 4; mi++)
      av[mi] = *(const bf16x8*)&As[((wm*4 + mi)*64 + lane)*8];
    #pragma unroll
    for (int nj = 0; nj < 4; nj++)
      bv[nj] = *(const bf16x8*)&Bs[((wn*4 + nj)*64 + lane)*8];
    #pragma unroll
    for (int mi = 0; mi < 4; mi++)
      #pragma unroll
      for (int nj = 0; nj < 4; nj++)
        acc[mi][nj] = __builtin_amdgcn_mfma_f32_16x16x32_bf16(av[mi], bv[nj], acc[mi][nj], 0, 0, 0);
    __syncthreads();
  }
  const int ldc = gridDim.y * 128;
  #pragma unroll
  for (int mi = 0; mi < 4; mi++)
    #pragma unroll
    for (int nj = 0; nj < 4; nj++){
      int rm0 = blockIdx.x*128 + wm*64 + mi*16 + (lane >> 4) * 4;
      int cn  = blockIdx.y*128 + wn*64 + nj*16 + (lane & 15);
      #pragma unroll
      for (int j = 0; j < 4; j++)
        g.C[(size_t)(rm0 + j) * ldc + cn] = (short)f2bf(acc[mi][nj][j] * g.scale);
    }
}

// ---------------- mega-kernel: whole network, X in registers ----------------
// Block = 16 batches (128 X-rows). Wave = batch-pair (16 rows, lane&15 = row).
// xf: A-frag layout (d = (lane>>4)*8 + e + 32c). xr[a][jj]: C-layout
// (row i_=(lane>>4)*4+jj, col n=(a>>3)*128+(a&7)*16+(lane&15)).
__global__ __launch_bounds__(512, 4) void k_net(
    const float* __restrict__ rf, const short* __restrict__ WiT,
    const float* __restrict__ bi, const float* __restrict__ emb,
    const short* __restrict__ Wqk, const short* __restrict__ Wvo,
    const float* __restrict__ ckv, const float* __restrict__ cvov,
    const float* __restrict__ lng, const float* __restrict__ lnb,
    const short* __restrict__ WpT, const float* __restrict__ bpv,
    const float* __restrict__ lpg, const float* __restrict__ lpb,
    float* __restrict__ outp){
  const int tid = threadIdx.x, lane = tid & 63, w = tid >> 6;
  const int b0 = blockIdx.x * 16;
  const int dsub = (lane >> 4) * 8;
  __shared__ alignas(16) short tst[8][2048];     // 32 KB multi-purpose
  __shared__ alignas(16) float atn[8][16][16];   // 8 KB
  __shared__ short ckb[256];
  __shared__ float s_add[256], s_g[256], s_b[256];
  __shared__ float redS[8][16], redQ[8][16], s_mean[16], s_rstd[16];

  #define LKW asm volatile("s_waitcnt lgkmcnt(0)" ::: "memory")

  // ===== input projection: h = rf@Wi + bi (per-wave N-slice, B direct-global) =====
  float* hst  = (float*)&tst[0][0];   // [16][264] f32
  float* embs = hst + 16*264;         // [8][256]  f32
  float* bis  = embs + 2048;          // [256]     f32
  if (tid < 256) bis[tid] = bi[tid];
  for (int i = tid; i < 2048; i += 512) embs[i] = emb[i];
  f32x4 hacc[2] = {};
  #pragma unroll
  for (int kk = 0; kk < 16; kk++){
    const float* ap = rf + (size_t)(b0 + (lane & 15)) * 512 + kk*32 + dsub;
    float4 a0 = *(const float4*)ap, a1 = *(const float4*)(ap + 4);
    float af[8] = {a0.x,a0.y,a0.z,a0.w,a1.x,a1.y,a1.z,a1.w};
    bf16x8 av = pk8(af);
    #pragma unroll
    for (int nj = 0; nj < 2; nj++){
      bf16x8 bv = *(const bf16x8*)(WiT + (size_t)(w*32 + nj*16 + (lane & 15))*512 + kk*32 + dsub);
      hacc[nj] = __builtin_amdgcn_mfma_f32_16x16x32_bf16(av, bv, hacc[nj], 0, 0, 0);
    }
  }
  __syncthreads();   // bis/embs published
  #pragma unroll
  for (int nj = 0; nj < 2; nj++)
    #pragma unroll
    for (int jj = 0; jj < 4; jj++){
      int m = (lane >> 4)*4 + jj, col = w*32 + nj*16 + (lane & 15);
      hst[m*264 + col] = hacc[nj][jj] + bis[col];
    }
  __syncthreads();   // hst published
  // build xf (A-layout) and xr (C-layout), both bf16(h + bi + emb)
  bf16x8 xf[8];
  short xr[16][4];
  {
    int r15 = lane & 15;
    int bt = w*2 + (r15 >> 3), ct = r15 & 7;
    #pragma unroll
    for (int c = 0; c < 8; c++){
      float v8[8];
      #pragma unroll
      for (int e = 0; e < 8; e++){
        int d = dsub + 32*c + e;
        v8[e] = hst[bt*264 + d] + embs[ct*256 + d];
      }
      xf[c] = pk8(v8);
    }
    #pragma unroll
    for (int a = 0; a < 16; a++)
      #pragma unroll
      for (int jj = 0; jj < 4; jj++){
        int i_ = (lane >> 4)*4 + jj;
        int n  = (a >> 3)*128 + (a & 7)*16 + r15;
        xr[a][jj] = (short)f2bf(hst[(w*2 + (i_ >> 3))*264 + n] + embs[(i_ & 7)*256 + n]);
      }
  }

  const unsigned long long MASK64 = 0x02191D69752B857EULL;   // ADJ[n][m] at bit n*8+m

  // ===== layers =====
  #pragma unroll 1
  for (int l = 0; l < 3; ++l){
    __syncthreads();   // protect s_*/ckb readers of prev layer + hst readers (l==0)
    if (tid < 256){
      ckb[tid]   = (short)f2bf(ckv[l*256 + tid]);
      s_add[tid] = cvov[l*256 + tid];
      s_g[tid]   = lng[l*256 + tid];
      s_b[tid]   = lnb[l*256 + tid];
    }
    const short* Wq_ = Wqk + l*65536;
    const short* Wv_ = Wvo + l*65536;
    __syncthreads();   // publish

    // ---- GEMM1: T = X @ Wqk (B direct-global); scores via stash-MFMA ----
    f32x4 sacc = {0.f, 0.f, 0.f, 0.f};
    #pragma unroll
    for (int h = 0; h < 2; h++){
      f32x4 acc[8] = {};
      #pragma unroll
      for (int kk = 0; kk < 8; kk++)
        #pragma unroll
        for (int nj = 0; nj < 8; nj++){
          bf16x8 bv = *(const bf16x8*)(Wq_ + (size_t)(h*128 + nj*16 + (lane & 15))*256 + kk*32 + dsub);
          acc[nj] = __builtin_amdgcn_mfma_f32_16x16x32_bf16(xf[kk], bv, acc[nj], 0, 0, 0);
        }
      #pragma unroll
      for (int nj = 0; nj < 8; nj++)
        #pragma unroll
        for (int jj = 0; jj < 4; jj++){
          int i_ = (lane >> 4)*4 + jj, nl = nj*16 + (lane & 15);
          tst[w][(nl >> 5)*512 + (i_ + 16*((nl >> 3) & 3))*8 + (nl & 7)] = (short)f2bf(acc[nj][jj]);
        }
      LKW; __builtin_amdgcn_sched_barrier(0);
      #pragma unroll
      for (int cl = 0; cl < 4; cl++){
        bf16x8 tf = *(const bf16x8*)&tst[w][cl*512 + lane*8];
        sacc = __builtin_amdgcn_mfma_f32_16x16x32_bf16(tf, xf[h*4 + cl], sacc, 0, 0, 0);
      }
      LKW;   // reads drained before next-half overwrite
    }

    // ---- skv[m] = X[m].ck ----
    float skv = 0.f;
    #pragma unroll
    for (int c = 0; c < 8; c++){
      bf16x8 cv = *(const bf16x8*)&ckb[c*32 + dsub];
      #pragma unroll
      for (int e = 0; e < 8; e++) skv = fmaf(bfs(xf[c][e]), bfs(cv[e]), skv);
    }
    skv += __shfl_xor(skv, 16); skv += __shfl_xor(skv, 32);

    // ---- softmax (C-layout) -> atn[w] ----
    #pragma unroll
    for (int jj = 0; jj < 4; jj++){
      int i_ = (lane >> 4)*4 + jj, j_ = lane & 15;
      bool ok = (((i_ ^ j_) & 8) == 0) &&
                ((MASK64 >> (((i_ & 7) << 3) | (j_ & 7))) & 1ull);
      float sv = ok ? (sacc[jj] + skv) : -3.0e38f;
      float mx = sv;
      mx = fmaxf(mx, __shfl_xor(mx, 1));
      mx = fmaxf(mx, __shfl_xor(mx, 2));
      mx = fmaxf(mx, __shfl_xor(mx, 4));
      float e = ok ? __expf(sv - mx) : 0.f;
      float sum = e;
      sum += __shfl_xor(sum, 1); sum += __shfl_xor(sum, 2); sum += __shfl_xor(sum, 4);
      atn[w][i_][j_] = e / sum;
    }
    LKW;   // own-wave atn writes -> reads

    // ---- PV: yfrag (A-layout) via shfl from xf ----
    bf16x8 yfrag[8];
    {
      float4 A0 = *(const float4*)&atn[w][lane & 15][lane & 8];
      float4 A1 = *(const float4*)&atn[w][lane & 15][(lane & 8) + 4];
      float am[8] = {A0.x, A0.y, A0.z, A0.w, A1.x, A1.y, A1.z, A1.w};
      #pragma unroll
      for (int c = 0; c < 8; c++){
        float a8[8] = {0,0,0,0,0,0,0,0};
        #pragma unroll
        for (int mi = 0; mi < 8; mi++){
          bf16x8 xs = shfl8(xf[c], (lane & 48) | (lane & 8) | mi);
          #pragma unroll
          for (int e = 0; e < 8; e++) a8[e] = fmaf(am[mi], bfs(xs[e]), a8[e]);
        }
        yfrag[c] = pk8(a8);
      }
    }

    // ---- GEMM2: out = y @ Wvo (B direct-global); t = out + cvo + xr in-place ----
    float rs[4] = {0,0,0,0}, rq[4] = {0,0,0,0};
    #pragma unroll
    for (int h = 0; h < 2; h++){
      f32x4 acc[8] = {};
      #pragma unroll
      for (int kk = 0; kk < 8; kk++)
        #pragma unroll
        for (int nj = 0; nj < 8; nj++){
          bf16x8 bv = *(const bf16x8*)(Wv_ + (size_t)(h*128 + nj*16 + (lane & 15))*256 + kk*32 + dsub);
          acc[nj] = __builtin_amdgcn_mfma_f32_16x16x32_bf16(yfrag[kk], bv, acc[nj], 0, 0, 0);
        }
      #pragma unroll
      for (int nj = 0; nj < 8; nj++){
        int a = h*8 + nj, n = h*128 + nj*16 + (lane & 15);
        float sadd = s_add[n];
        #pragma unroll
        for (int jj = 0; jj < 4; jj++){
          float t = acc[nj][jj] + sadd + bfs(xr[a][jj]);
          xr[a][jj] = (short)f2bf(t);
          rs[jj] += t; rq[jj] = fmaf(t, t, rq[jj]);
        }
      }
    }
    // ---- LN stats (row i_ over 256 cols: 16 a-slots + 16 lanes) ----
    float mean[4], rstd[4];
    #pragma unroll
    for (int jj = 0; jj < 4; jj++){
      float s = rs[jj], q = rq[jj];
      s += __shfl_xor(s, 1); q += __shfl_xor(q, 1);
      s += __shfl_xor(s, 2); q += __shfl_xor(q, 2);
      s += __shfl_xor(s, 4); q += __shfl_xor(q, 4);
      s += __shfl_xor(s, 8); q += __shfl_xor(q, 8);
      mean[jj] = s * (1.f/256.f);
      float var = q * (1.f/256.f) - mean[jj]*mean[jj];
      rstd[jj] = rsqrtf(fmaxf(var, 0.f) + 1e-5f);
    }
    // ---- LN apply in C-layout -> new xr ----
    #pragma unroll
    for (int a = 0; a < 16; a++){
      int n = (a >> 3)*128 + (a & 7)*16 + (lane & 15);
      float gg = s_g[n], bb = s_b[n];
      #pragma unroll
      for (int jj = 0; jj < 4; jj++){
        float v = (bfs(xr[a][jj]) - mean[jj]) * rstd[jj] * gg + bb;
        xr[a][jj] = (short)f2bf(v);
      }
    }
    // ---- rebuild xf from xr via per-wave tst stash (per half) ----
    #pragma unroll
    for (int h = 0; h < 2; h++){
      #pragma unroll
      for (int nj = 0; nj < 8; nj++)
        #pragma unroll
        for (int jj = 0; jj < 4; jj++){
          int i_ = (lane >> 4)*4 + jj, nl = nj*16 + (lane & 15);
          tst[w][(nl >> 5)*512 + (i_ + 16*((nl >> 3) & 3))*8 + (nl & 7)] = xr[h*8 + nj][jj];
        }
      LKW; __builtin_amdgcn_sched_barrier(0);
      #pragma unroll
      for (int cl = 0; cl < 4; cl++)
        xf[h*4 + cl] = *(const bf16x8*)&tst[w][cl*512 + lane*8];
      LKW;
    }
  } // layers

  // ===== head: GDP-reduce -> Astage -> GEMM vs WpT -> LN -> GELU =====
  __syncthreads();   // tst becomes cross-wave Astage
  short* Ast = &tst[0][0];   // [16][264] bf16
  {
    int c7 = lane & 7;
    float g = (c7 == 0) ? 0.4f : (c7 == 1) ? 0.15f : (c7 == 2) ? 0.12f :
              (c7 == 3) ? 0.1f : (c7 == 4) ? 0.08f : (c7 == 5) ? 0.08f :
              (c7 == 6) ? 0.05f : 0.02f;
    #pragma unroll
    for (int c = 0; c < 8; c++){
      float v8[8];
      #pragma unroll
      for (int e = 0; e < 8; e++){
        float v = g * bfs(xf[c][e]);
        v += __shfl_xor(v, 1); v += __shfl_xor(v, 2); v += __shfl_xor(v, 4);
        v8[e] = v;
      }
      if ((lane & 7) == 0){
        int bt = w*2 + ((lane >> 3) & 1);
        *(bf16x8*)&Ast[bt*264 + dsub + 32*c] = pk8(v8);
      }
    }
  }
  __syncthreads();
  f32x4 ha[2] = {};
  #pragma unroll
  for (int kk = 0; kk < 8; kk++){
    bf16x8 av = *(const bf16x8*)&Ast[(lane & 15)*264 + kk*32 + dsub];
    #pragma unroll
    for (int nj = 0; nj < 2; nj++){
      bf16x8 bv = *(const bf16x8*)(WpT + (size_t)(w*32 + nj*16 + (lane & 15))*256 + kk*32 + dsub);
      ha[nj] = __builtin_amdgcn_mfma_f32_16x16x32_bf16(av, bv, ha[nj], 0, 0, 0);
    }
  }
  #pragma unroll
  for (int jj = 0; jj < 4; jj++){
    float s = 0.f, q = 0.f;
    #pragma unroll
    for (int nj = 0; nj < 2; nj++){
      int cx = w*32 + nj*16 + (lane & 15);
      float t = ha[nj][jj] + bpv[cx];
      ha[nj][jj] = t;
      s += t; q = fmaf(t, t, q);
    }
    s += __shfl_xor(s, 1); q += __shfl_xor(q, 1);
    s += __shfl_xor(s, 2); q += __shfl_xor(q, 2);
    s += __shfl_xor(s, 4); q += __shfl_xor(q, 4);
    s += __shfl_xor(s, 8); q += __shfl_xor(q, 8);
    if ((lane & 15) == 0){
      int rl = (lane >> 4)*4 + jj;
      redS[w][rl] = s; redQ[w][rl] = q;
    }
  }
  __syncthreads();
  if (tid < 16){
    float sm = 0.f, sq = 0.f;
    #pragma unroll
    for (int w2 = 0; w2 < 8; w2++){ sm += redS[w2][tid]; sq += redQ[w2][tid]; }
    float mn = sm * (1.f/256.f);
    float var = sq * (1.f/256.f) - mn*mn;
    s_mean[tid] = mn;
    s_rstd[tid] = rsqrtf(fmaxf(var, 0.f) + 1e-5f);
  }
  __syncthreads();
  #pragma unroll
  for (int jj = 0; jj < 4; jj++){
    int rl = (lane >> 4)*4 + jj;
    float mn = s_mean[rl], rstd = s_rstd[rl];
    #pragma unroll
    for (int nj = 0; nj < 2; nj++){
      int cx = w*32 + nj*16 + (lane & 15);
      float y = (ha[nj][jj] - mn) * rstd * lpg[cx] + lpb[cx];
      outp[(size_t)(b0 + rl)*256 + cx] = 0.5f * y * (1.0f + erff(y * 0.70710678118654752f));
    }
  }
  #undef LKW
}

extern "C" void kernel_launch(void* const* d_in, const int* in_sizes, int n_in,
                              void* d_out, int out_size, void* d_ws, size_t ws_size,
                              hipStream_t stream){
  (void)in_sizes; (void)n_in; (void)out_size; (void)ws_size;
  const float* rf  = (const float*)d_in[0];
  const float* Wi  = (const float*)d_in[1];
  const float* bi  = (const float*)d_in[2];
  const float* emb = (const float*)d_in[3];
  const float* Wq  = (const float*)d_in[4];
  const float* bq  = (const float*)d_in[5];
  const float* Wk  = (const float*)d_in[6];
  const float* bk  = (const float*)d_in[7];
  const float* Wv  = (const float*)d_in[8];
  const float* bv  = (const float*)d_in[9];
  const float* Wo  = (const float*)d_in[10];
  const float* bo  = (const float*)d_in[11];
  const float* lng = (const float*)d_in[12];
  const float* lnb = (const float*)d_in[13];
  const float* Wp  = (const float*)d_in[14];
  const float* bp  = (const float*)d_in[15];
  const float* lpg = (const float*)d_in[16];
  const float* lpb = (const float*)d_in[17];

  char* ws = (char*)d_ws;
  short* Wqb  = (short*)(ws);                      // [3][256][1024] bf16
  short* Wkb  = (short*)(ws + 1572864ull);
  short* Wvb  = (short*)(ws + 3145728ull);
  short* WoTb = (short*)(ws + 4718592ull);         // [3][256][1024]
  short* WiTb = (short*)(ws + 6291456ull);         // [256][512]
  short* WpTb = (short*)(ws + 6553600ull);         // [256][256]
  short* Wqk  = (short*)(ws + 6684672ull);         // [3][256][256] Bt, pre-scaled 1/16
  short* Wvo  = (short*)(ws + 7077888ull);         // [3][256][256] Bt
  float* cqv  = (float*)(ws + 7471104ull);
  float* ckv  = (float*)(ws + 7474176ull);
  float* cvov = (float*)(ws + 7477248ull);
  float* c0v  = (float*)(ws + 7480320ull);

  { CvP cv;
    cv.src[0]=Wq; cv.dst[0]=Wqb;
    cv.src[1]=Wk; cv.dst[1]=Wkb;
    cv.src[2]=Wv; cv.dst[2]=Wvb;
    cv.src[3]=Wv; cv.dst[3]=Wvb;   // unused slot
    cv.boff[0]=0; cv.boff[1]=384; cv.boff[2]=768; cv.boff[3]=1152; cv.boff[4]=1152;
    k_convert<<<dim3(1152), dim3(256), 0, stream>>>(cv); }

  { TrP tp;
    tp.src[0]=Wi;          tp.dst[0]=WiTb;          tp.rows[0]=512;  tp.cols[0]=256;
    tp.src[1]=Wo;          tp.dst[1]=WoTb;          tp.rows[1]=1024; tp.cols[1]=256;
    tp.src[2]=Wo+262144;   tp.dst[2]=WoTb+262144;   tp.rows[2]=1024; tp.cols[2]=256;
    tp.src[3]=Wo+524288;   tp.dst[3]=WoTb+524288;   tp.rows[3]=1024; tp.cols[3]=256;
    tp.src[4]=Wp;          tp.dst[4]=WpTb;          tp.rows[4]=256;  tp.cols[4]=256;
    tp.toff[0]=0; tp.toff[1]=32; tp.toff[2]=96; tp.toff[3]=160; tp.toff[4]=224; tp.toff[5]=240;
    k_transpose<<<dim3(240), dim3(256), 0, stream>>>(tp); }

  k_vecs2<<<dim3(4, 3), dim3(256), 0, stream>>>(Wqb, Wkb, WoTb, bq, bk, bv, bo,
                                                cqv, ckv, cvov, c0v);

  { GemmP g{};
    for (int l = 0; l < 3; l++){
      g.d[l]   = GDesc{ Wkb  + l*262144, Wqb + l*262144, Wqk + l*65536, 1024, 0.0625f };
      g.d[3+l] = GDesc{ WoTb + l*262144, Wvb + l*262144, Wvo + l*65536, 1024, 1.0f };
    }
    k_gemm128<<<dim3(2,2,6), dim3(256), 0, stream>>>(g); }

  k_net<<<dim3(512), dim3(512), 0, stream>>>(rf, WiTb, bi, emb, Wqk, Wvo,
      ckv, cvov, lng, lnb, WpTb, bp, lpg, lpb, (float*)d_out);
}

// Round 9
// 583.219 us; speedup vs baseline: 1.2273x; 1.2273x over previous
//
#include <hip/hip_runtime.h>
#include <math.h>

// RegionalGNN: B=8192, NC=8, H=256, HD=1024, L=3.
// R9: mega-kernel k_net, X in ONE register layout (xf, A-frag). Residual handled
//     through the per-wave 8KB LDS stash: pre-GEMM2 stash xf; epilogue reads
//     residual via C-layout scalar reads, writes t back in place, LN-apply reads
//     A-layout contiguous -> new xf. Removes xr (R8's 64-VGPR short array) ->
//     peak live ~100 VGPR, no spill. (R8: WRITE_SIZE 784MB = scratch thrash.)

typedef short bf16x8 __attribute__((ext_vector_type(8)));
typedef float f32x4  __attribute__((ext_vector_type(4)));

__device__ __forceinline__ float bflo(unsigned int u){ return __uint_as_float(u << 16); }
__device__ __forceinline__ float bfhi(unsigned int u){ return __uint_as_float(u & 0xffff0000u); }
__device__ __forceinline__ float bfs(short s){ return __uint_as_float((unsigned int)(unsigned short)s << 16); }
__device__ __forceinline__ unsigned short f2bf(float f){
  unsigned int u = __float_as_uint(f);
  u += 0x7fffu + ((u >> 16) & 1u);          // RNE
  return (unsigned short)(u >> 16);
}
__device__ __forceinline__ void unpack8(uint4 a, float* o){
  o[0]=bflo(a.x); o[1]=bfhi(a.x); o[2]=bflo(a.y); o[3]=bfhi(a.y);
  o[4]=bflo(a.z); o[5]=bfhi(a.z); o[6]=bflo(a.w); o[7]=bfhi(a.w);
}
__device__ __forceinline__ uint4 pack8(const float* v){
  uint4 r;
  r.x = (unsigned int)f2bf(v[0]) | ((unsigned int)f2bf(v[1]) << 16);
  r.y = (unsigned int)f2bf(v[2]) | ((unsigned int)f2bf(v[3]) << 16);
  r.z = (unsigned int)f2bf(v[4]) | ((unsigned int)f2bf(v[5]) << 16);
  r.w = (unsigned int)f2bf(v[6]) | ((unsigned int)f2bf(v[7]) << 16);
  return r;
}
__device__ __forceinline__ void gload16(const void* g, void* l){
  __builtin_amdgcn_global_load_lds(
      (const __attribute__((address_space(1))) unsigned int*)g,
      (__attribute__((address_space(3))) unsigned int*)l, 16, 0, 0);
}
__device__ __forceinline__ bf16x8 shfl8(bf16x8 v, int src){
  union U { bf16x8 h; int u[4]; };
  U a, r; a.h = v;
  #pragma unroll
  for (int j = 0; j < 4; j++) r.u[j] = __shfl(a.u[j], src);
  return r.h;
}
__device__ __forceinline__ bf16x8 pk8(const float* v){
  bf16x8 r;
  #pragma unroll
  for (int j = 0; j < 8; j++) r[j] = (short)f2bf(v[j]);
  return r;
}

// ---------------- convert f32 -> bf16 (Wq, Wk, Wv) ----------------
struct CvP { const float* src[4]; short* dst[4]; int boff[5]; };
__global__ __launch_bounds__(256) void k_convert(CvP p){
  int bid = blockIdx.x, s = 0;
  while (bid >= p.boff[s+1]) s++;
  size_t e = (size_t)(bid - p.boff[s]) * 2048 + (size_t)threadIdx.x * 8;
  const float* src = p.src[s] + e;
  float4 v0 = *(const float4*)src;
  float4 v1 = *(const float4*)(src + 4);
  float v[8] = {v0.x,v0.y,v0.z,v0.w,v1.x,v1.y,v1.z,v1.w};
  *(uint4*)(p.dst[s] + e) = pack8(v);
}

// ---------------- transpose + convert (Wi, Wo x3, Wp) ----------------
struct TrP { const float* src[5]; short* dst[5]; int rows[5]; int cols[5]; int toff[6]; };
__global__ __launch_bounds__(256) void k_transpose(TrP p){
  __shared__ float tile[64][65];
  int bid = blockIdx.x, s = 0;
  while (bid >= p.toff[s+1]) s++;
  int ti = bid - p.toff[s];
  int cols = p.cols[s], rows = p.rows[s];
  int ntc = cols >> 6;
  int r0 = (ti / ntc) * 64, c0 = (ti % ntc) * 64;
  const float* src = p.src[s];
  int row = threadIdx.x >> 2, jb = (threadIdx.x & 3) * 16;
  #pragma unroll
  for (int j = 0; j < 16; j += 4){
    float4 v = *(const float4*)(src + (size_t)(r0 + row) * cols + c0 + jb + j);
    tile[row][jb+j] = v.x; tile[row][jb+j+1] = v.y; tile[row][jb+j+2] = v.z; tile[row][jb+j+3] = v.w;
  }
  __syncthreads();
  short* dst = p.dst[s];
  float tmp[16];
  #pragma unroll
  for (int j = 0; j < 16; j++) tmp[j] = tile[jb + j][row];
  #pragma unroll
  for (int j = 0; j < 16; j += 8)
    *(uint4*)(dst + (size_t)(c0 + row) * rows + r0 + jb + j) = pack8(&tmp[j]);
}

// ---------------- bias-fold vectors via bf16 row-dots ----------------
__global__ __launch_bounds__(256) void k_vecs2(
    const short* Wqb, const short* Wkb, const short* WoTb,
    const float* bq, const float* bk, const float* bv, const float* bo,
    float* cq, float* ck, float* cvo, float* c0){
  const int job = blockIdx.x, l = blockIdx.y, tid = threadIdx.x;
  __shared__ float sv[1024];
  __shared__ float red[256];
  if (job == 3){
    float pp = 0.f;
    #pragma unroll
    for (int i = 0; i < 4; i++){
      int d = tid*4 + i;
      pp = fmaf(bq[l*1024 + d], bk[l*1024 + d], pp);
    }
    red[tid] = pp; __syncthreads();
    for (int o = 128; o > 0; o >>= 1){ if (tid < o) red[tid] += red[tid + o]; __syncthreads(); }
    if (tid == 0) c0[l] = red[0] * 0.0625f;
    return;
  }
  const short* rows = (job==0 ? Wqb : job==1 ? Wkb : WoTb) + (size_t)l*262144;
  const float* vecg = (job==0 ? bk : job==1 ? bq : bv) + l*1024;
  const float scale = (job == 2) ? 1.0f : 0.0625f;
  for (int i = tid; i < 1024; i += 256) sv[i] = vecg[i];
  __syncthreads();
  const int row = tid >> 3, sub = tid & 7;
  for (int pass = 0; pass < 8; pass++){
    int r = pass*32 + row;
    const short* rp = rows + (size_t)r*1024;
    float acc = 0.f;
    #pragma unroll
    for (int i = 0; i < 16; i++){
      int d = sub*8 + i*64;
      uint4 v = *(const uint4*)(rp + d);
      float f[8]; unpack8(v, f);
      #pragma unroll
      for (int j = 0; j < 8; j++) acc = fmaf(f[j], sv[d + j], acc);
    }
    acc += __shfl_xor(acc, 1); acc += __shfl_xor(acc, 2); acc += __shfl_xor(acc, 4);
    if (sub == 0){
      float o = acc * scale;
      if (job == 2) o += bo[l*256 + r];
      (job==0 ? cq : job==1 ? ck : cvo)[l*256 + r] = o;
    }
  }
}

// ---------------- 128x128 MFMA GEMM (weight precompute only) ----------------
struct GDesc { const short* A; const short* Bt; short* C; int K; float scale; };
struct GemmP { GDesc d[6]; };
__global__ __launch_bounds__(256) void k_gemm128(GemmP p){
  GDesc g = p.d[blockIdx.z];
  const int tid = threadIdx.x, lane = tid & 63, w = tid >> 6;
  const int wm = w >> 1, wn = w & 1;
  __shared__ alignas(16) short As[128*32];
  __shared__ alignas(16) short Bs[128*32];
  const int K = g.K;
  const short* Ab = g.A + (size_t)blockIdx.x * 128 * K;
  const short* Bb = g.Bt + (size_t)blockIdx.y * 128 * K;
  f32x4 acc[4][4] = {};
  for (int k0 = 0; k0 < K; k0 += 32){
    #pragma unroll
    for (int i = 0; i < 2; i++){
      int s = w*2 + i;
      int ro = (s >> 2)*64 + (s & 3)*16 + (lane & 15);
      int co = k0 + (lane >> 4) * 8;
      gload16(Ab + (size_t)ro * K + co, &As[s*512]);
      gload16(Bb + (size_t)ro * K + co, &Bs[s*512]);
    }
    __syncthreads();
    bf16x8 av[4], bv[4];
    #pragma unroll
    for (int mi = 0; mi < 4; mi++)
      av[mi] = *(const bf16x8*)&As[((wm*4 + mi)*64 + lane)*8];
    #pragma unroll
    for (int nj = 0; nj < 4; nj++)
      bv[nj] = *(const bf16x8*)&Bs[((wn*4 + nj)*64 + lane)*8];
    #pragma unroll
    for (int mi = 0; mi < 4; mi++)
      #pragma unroll
      for (int nj = 0; nj < 4; nj++)
        acc[mi][nj] = __builtin_amdgcn_mfma_f32_16x16x32_bf16(av[mi], bv[nj], acc[mi][nj], 0, 0, 0);
    __syncthreads();
  }
  const int ldc = gridDim.y * 128;
  #pragma unroll
  for (int mi = 0; mi < 4; mi++)
    #pragma unroll
    for (int nj = 0; nj < 4; nj++){
      int rm0 = blockIdx.x*128 + wm*64 + mi*16 + (lane >> 4) * 4;
      int cn  = blockIdx.y*128 + wn*64 + nj*16 + (lane & 15);
      #pragma unroll
      for (int j = 0; j < 4; j++)
        g.C[(size_t)(rm0 + j) * ldc + cn] = (short)f2bf(acc[mi][nj][j] * g.scale);
    }
}

// ---------------- mega-kernel: whole network, X in registers (one layout) ----------------
// Block = 16 batches (128 X-rows). Wave = batch-pair (16 rows, lane&15 = row).
// xf: A-frag layout, element (r,d) at lane(r + 16*((d&31)>>3)), chunk c=d>>5, elem d&7.
// Stash addr of (r,d) in tst[w]: (d>>5)*512 + (r + 16*((d>>3)&3))*8 + (d&7).
__global__ __launch_bounds__(512, 4) void k_net(
    const float* __restrict__ rf, const short* __restrict__ WiT,
    const float* __restrict__ bi, const float* __restrict__ emb,
    const short* __restrict__ Wqk, const short* __restrict__ Wvo,
    const float* __restrict__ ckv, const float* __restrict__ cvov,
    const float* __restrict__ lng, const float* __restrict__ lnb,
    const short* __restrict__ WpT, const float* __restrict__ bpv,
    const float* __restrict__ lpg, const float* __restrict__ lpb,
    float* __restrict__ outp){
  const int tid = threadIdx.x, lane = tid & 63, w = tid >> 6;
  const int b0 = blockIdx.x * 16;
  const int dsub = (lane >> 4) * 8;
  __shared__ alignas(16) short tst[8][4096];     // 64 KB: per-wave 8KB stash
  __shared__ alignas(16) float atn[8][16][16];   // 8 KB: attn probs / LN stats
  __shared__ short ckb[256];
  __shared__ float s_add[256], s_g[256], s_b[256];
  __shared__ float redS[8][16], redQ[8][16], s_mean[16], s_rstd[16];

  #define LKW asm volatile("s_waitcnt lgkmcnt(0)" ::: "memory")

  // ===== input projection: h = rf@Wi + bi (per-wave N-slice, B direct-global) =====
  float* hst  = (float*)&tst[0][0];   // [16][264] f32
  float* embs = hst + 16*264;         // [8][256]  f32
  float* bis  = embs + 2048;          // [256]     f32
  if (tid < 256) bis[tid] = bi[tid];
  for (int i = tid; i < 2048; i += 512) embs[i] = emb[i];
  f32x4 hacc[2] = {};
  #pragma unroll
  for (int kk = 0; kk < 16; kk++){
    const float* ap = rf + (size_t)(b0 + (lane & 15)) * 512 + kk*32 + dsub;
    float4 a0 = *(const float4*)ap, a1 = *(const float4*)(ap + 4);
    float af[8] = {a0.x,a0.y,a0.z,a0.w,a1.x,a1.y,a1.z,a1.w};
    bf16x8 av = pk8(af);
    #pragma unroll
    for (int nj = 0; nj < 2; nj++){
      bf16x8 bv = *(const bf16x8*)(WiT + (size_t)(w*32 + nj*16 + (lane & 15))*512 + kk*32 + dsub);
      hacc[nj] = __builtin_amdgcn_mfma_f32_16x16x32_bf16(av, bv, hacc[nj], 0, 0, 0);
    }
  }
  __syncthreads();   // bis/embs published
  #pragma unroll
  for (int nj = 0; nj < 2; nj++)
    #pragma unroll
    for (int jj = 0; jj < 4; jj++){
      int m = (lane >> 4)*4 + jj, col = w*32 + nj*16 + (lane & 15);
      hst[m*264 + col] = hacc[nj][jj] + bis[col];
    }
  __syncthreads();   // hst published
  // build xf (A-layout) = bf16(h + bi + emb)
  bf16x8 xf[8];
  {
    int r15 = lane & 15;
    int bt = w*2 + (r15 >> 3), ct = r15 & 7;
    #pragma unroll
    for (int c = 0; c < 8; c++){
      float v8[8];
      #pragma unroll
      for (int e = 0; e < 8; e++){
        int d = dsub + 32*c + e;
        v8[e] = hst[bt*264 + d] + embs[ct*256 + d];
      }
      xf[c] = pk8(v8);
    }
  }

  const unsigned long long MASK64 = 0x02191D69752B857EULL;   // ADJ[n][m] at bit n*8+m

  // ===== layers =====
  #pragma unroll 1
  for (int l = 0; l < 3; ++l){
    __syncthreads();   // protect hst readers (l==0) / prev-layer s_* readers
    if (tid < 256){
      ckb[tid]   = (short)f2bf(ckv[l*256 + tid]);
      s_add[tid] = cvov[l*256 + tid];
      s_g[tid]   = lng[l*256 + tid];
      s_b[tid]   = lnb[l*256 + tid];
    }
    const short* Wq_ = Wqk + l*65536;
    const short* Wv_ = Wvo + l*65536;
    __syncthreads();   // publish

    // ---- GEMM1: T = X @ Wqk (B direct-global); scores via stash-MFMA ----
    f32x4 sacc = {0.f, 0.f, 0.f, 0.f};
    #pragma unroll
    for (int h = 0; h < 2; h++){
      f32x4 acc[8] = {};
      #pragma unroll
      for (int kk = 0; kk < 8; kk++)
        #pragma unroll
        for (int nj = 0; nj < 8; nj++){
          bf16x8 bv = *(const bf16x8*)(Wq_ + (size_t)(h*128 + nj*16 + (lane & 15))*256 + kk*32 + dsub);
          acc[nj] = __builtin_amdgcn_mfma_f32_16x16x32_bf16(xf[kk], bv, acc[nj], 0, 0, 0);
        }
      #pragma unroll
      for (int nj = 0; nj < 8; nj++)
        #pragma unroll
        for (int jj = 0; jj < 4; jj++){
          int i_ = (lane >> 4)*4 + jj, nl = nj*16 + (lane & 15);
          tst[w][(nl >> 5)*512 + (i_ + 16*((nl >> 3) & 3))*8 + (nl & 7)] = (short)f2bf(acc[nj][jj]);
        }
      LKW; __builtin_amdgcn_sched_barrier(0);
      #pragma unroll
      for (int cl = 0; cl < 4; cl++){
        bf16x8 tf = *(const bf16x8*)&tst[w][cl*512 + lane*8];
        sacc = __builtin_amdgcn_mfma_f32_16x16x32_bf16(tf, xf[h*4 + cl], sacc, 0, 0, 0);
      }
      LKW;   // reads drained before next-half overwrite
    }

    // ---- skv[m] = X[m].ck ----
    float skv = 0.f;
    #pragma unroll
    for (int c = 0; c < 8; c++){
      bf16x8 cv = *(const bf16x8*)&ckb[c*32 + dsub];
      #pragma unroll
      for (int e = 0; e < 8; e++) skv = fmaf(bfs(xf[c][e]), bfs(cv[e]), skv);
    }
    skv += __shfl_xor(skv, 16); skv += __shfl_xor(skv, 32);

    // ---- softmax (C-layout) -> atn[w] ----
    #pragma unroll
    for (int jj = 0; jj < 4; jj++){
      int i_ = (lane >> 4)*4 + jj, j_ = lane & 15;
      bool ok = (((i_ ^ j_) & 8) == 0) &&
                ((MASK64 >> (((i_ & 7) << 3) | (j_ & 7))) & 1ull);
      float sv = ok ? (sacc[jj] + skv) : -3.0e38f;
      float mx = sv;
      mx = fmaxf(mx, __shfl_xor(mx, 1));
      mx = fmaxf(mx, __shfl_xor(mx, 2));
      mx = fmaxf(mx, __shfl_xor(mx, 4));
      float e = ok ? __expf(sv - mx) : 0.f;
      float sum = e;
      sum += __shfl_xor(sum, 1); sum += __shfl_xor(sum, 2); sum += __shfl_xor(sum, 4);
      atn[w][i_][j_] = e / sum;
    }
    LKW;   // own-wave atn writes -> reads

    // ---- PV: yfrag (A-layout) via shfl from xf ----
    bf16x8 yfrag[8];
    {
      float4 A0 = *(const float4*)&atn[w][lane & 15][lane & 8];
      float4 A1 = *(const float4*)&atn[w][lane & 15][(lane & 8) + 4];
      float am[8] = {A0.x, A0.y, A0.z, A0.w, A1.x, A1.y, A1.z, A1.w};
      #pragma unroll
      for (int c = 0; c < 8; c++){
        float a8[8] = {0,0,0,0,0,0,0,0};
        #pragma unroll
        for (int mi = 0; mi < 8; mi++){
          bf16x8 xs = shfl8(xf[c], (lane & 48) | (lane & 8) | mi);
          #pragma unroll
          for (int e = 0; e < 8; e++) a8[e] = fmaf(am[mi], bfs(xs[e]), a8[e]);
        }
        yfrag[c] = pk8(a8);
      }
    }

    // ---- stash X (A-layout, contiguous b128) -> tst[w]; xf dead until LN-apply ----
    #pragma unroll
    for (int c = 0; c < 8; c++)
      *(bf16x8*)&tst[w][c*512 + lane*8] = xf[c];
    LKW; __builtin_amdgcn_sched_barrier(0);

    // ---- GEMM2 + epilogue per half: t = acc + cvo + X_res (from stash, C-layout) ----
    float rs[4] = {0,0,0,0}, rq[4] = {0,0,0,0};
    #pragma unroll
    for (int h = 0; h < 2; h++){
      f32x4 acc[8] = {};
      #pragma unroll
      for (int kk = 0; kk < 8; kk++)
        #pragma unroll
        for (int nj = 0; nj < 8; nj++){
          bf16x8 bv = *(const bf16x8*)(Wv_ + (size_t)(h*128 + nj*16 + (lane & 15))*256 + kk*32 + dsub);
          acc[nj] = __builtin_amdgcn_mfma_f32_16x16x32_bf16(yfrag[kk], bv, acc[nj], 0, 0, 0);
        }
      #pragma unroll
      for (int nj = 0; nj < 8; nj++){
        int n = h*128 + nj*16 + (lane & 15);
        float sadd = s_add[n];
        #pragma unroll
        for (int jj = 0; jj < 4; jj++){
          int i_ = (lane >> 4)*4 + jj;
          int ad = (n >> 5)*512 + (i_ + 16*((n >> 3) & 3))*8 + (n & 7);
          float t = acc[nj][jj] + sadd + bfs(tst[w][ad]);   // RAW same-lane: dep-ordered
          rs[jj] += t; rq[jj] = fmaf(t, t, rq[jj]);
          tst[w][ad] = (short)f2bf(t);                      // overwrite X slot with t
        }
      }
    }
    // ---- LN stats -> atn[w] scratch (attn probs dead) ----
    float* stp = &atn[w][0][0];
    #pragma unroll
    for (int jj = 0; jj < 4; jj++){
      float s = rs[jj], q = rq[jj];
      s += __shfl_xor(s, 1); q += __shfl_xor(q, 1);
      s += __shfl_xor(s, 2); q += __shfl_xor(q, 2);
      s += __shfl_xor(s, 4); q += __shfl_xor(q, 4);
      s += __shfl_xor(s, 8); q += __shfl_xor(q, 8);
      if ((lane & 15) == 0){
        int i_ = (lane >> 4)*4 + jj;
        float mn = s * (1.f/256.f);
        float var = q * (1.f/256.f) - mn*mn;
        stp[i_]      = mn;
        stp[16 + i_] = rsqrtf(fmaxf(var, 0.f) + 1e-5f);
      }
    }
    LKW; __builtin_amdgcn_sched_barrier(0);   // t-writes + stp visible within wave
    // ---- LN apply: read t (A-layout contiguous), row stats = row lane&15 ----
    {
      float mn = stp[lane & 15], rr = stp[16 + (lane & 15)];
      #pragma unroll
      for (int c = 0; c < 8; c++){
        bf16x8 tv = *(const bf16x8*)&tst[w][c*512 + lane*8];
        float v8[8];
        #pragma unroll
        for (int e = 0; e < 8; e++){
          int d = c*32 + dsub + e;
          v8[e] = (bfs(tv[e]) - mn) * rr * s_g[d] + s_b[d];
        }
        xf[c] = pk8(v8);
      }
    }
    LKW;   // stash reads drained before next layer reuses tst[w]
  } // layers

  // ===== head: GDP-reduce -> Astage -> GEMM vs WpT -> LN -> GELU =====
  __syncthreads();   // tst becomes cross-wave Astage
  short* Ast = &tst[0][0];   // [16][264] bf16
  {
    int c7 = lane & 7;
    float g = (c7 == 0) ? 0.4f : (c7 == 1) ? 0.15f : (c7 == 2) ? 0.12f :
              (c7 == 3) ? 0.1f : (c7 == 4) ? 0.08f : (c7 == 5) ? 0.08f :
              (c7 == 6) ? 0.05f : 0.02f;
    #pragma unroll
    for (int c = 0; c < 8; c++){
      float v8[8];
      #pragma unroll
      for (int e = 0; e < 8; e++){
        float v = g * bfs(xf[c][e]);
        v += __shfl_xor(v, 1); v += __shfl_xor(v, 2); v += __shfl_xor(v, 4);
        v8[e] = v;
      }
      if ((lane & 7) == 0){
        int bt = w*2 + ((lane >> 3) & 1);
        *(bf16x8*)&Ast[bt*264 + dsub + 32*c] = pk8(v8);
      }
    }
  }
  __syncthreads();
  f32x4 ha[2] = {};
  #pragma unroll
  for (int kk = 0; kk < 8; kk++){
    bf16x8 av = *(const bf16x8*)&Ast[(lane & 15)*264 + kk*32 + dsub];
    #pragma unroll
    for (int nj = 0; nj < 2; nj++){
      bf16x8 bv = *(const bf16x8*)(WpT + (size_t)(w*32 + nj*16 + (lane & 15))*256 + kk*32 + dsub);
      ha[nj] = __builtin_amdgcn_mfma_f32_16x16x32_bf16(av, bv, ha[nj], 0, 0, 0);
    }
  }
  #pragma unroll
  for (int jj = 0; jj < 4; jj++){
    float s = 0.f, q = 0.f;
    #pragma unroll
    for (int nj = 0; nj < 2; nj++){
      int cx = w*32 + nj*16 + (lane & 15);
      float t = ha[nj][jj] + bpv[cx];
      ha[nj][jj] = t;
      s += t; q = fmaf(t, t, q);
    }
    s += __shfl_xor(s, 1); q += __shfl_xor(q, 1);
    s += __shfl_xor(s, 2); q += __shfl_xor(q, 2);
    s += __shfl_xor(s, 4); q += __shfl_xor(q, 4);
    s += __shfl_xor(s, 8); q += __shfl_xor(q, 8);
    if ((lane & 15) == 0){
      int rl = (lane >> 4)*4 + jj;
      redS[w][rl] = s; redQ[w][rl] = q;
    }
  }
  __syncthreads();
  if (tid < 16){
    float sm = 0.f, sq = 0.f;
    #pragma unroll
    for (int w2 = 0; w2 < 8; w2++){ sm += redS[w2][tid]; sq += redQ[w2][tid]; }
    float mn = sm * (1.f/256.f);
    float var = sq * (1.f/256.f) - mn*mn;
    s_mean[tid] = mn;
    s_rstd[tid] = rsqrtf(fmaxf(var, 0.f) + 1e-5f);
  }
  __syncthreads();
  #pragma unroll
  for (int jj = 0; jj < 4; jj++){
    int rl = (lane >> 4)*4 + jj;
    float mn = s_mean[rl], rstd = s_rstd[rl];
    #pragma unroll
    for (int nj = 0; nj < 2; nj++){
      int cx = w*32 + nj*16 + (lane & 15);
      float y = (ha[nj][jj] - mn) * rstd * lpg[cx] + lpb[cx];
      outp[(size_t)(b0 + rl)*256 + cx] = 0.5f * y * (1.0f + erff(y * 0.70710678118654752f));
    }
  }
  #undef LKW
}

extern "C" void kernel_launch(void* const* d_in, const int* in_sizes, int n_in,
                              void* d_out, int out_size, void* d_ws, size_t ws_size,
                              hipStream_t stream){
  (void)in_sizes; (void)n_in; (void)out_size; (void)ws_size;
  const float* rf  = (const float*)d_in[0];
  const float* Wi  = (const float*)d_in[1];
  const float* bi  = (const float*)d_in[2];
  const float* emb = (const float*)d_in[3];
  const float* Wq  = (const float*)d_in[4];
  const float* bq  = (const float*)d_in[5];
  const float* Wk  = (const float*)d_in[6];
  const float* bk  = (const float*)d_in[7];
  const float* Wv  = (const float*)d_in[8];
  const float* bv  = (const float*)d_in[9];
  const float* Wo  = (const float*)d_in[10];
  const float* bo  = (const float*)d_in[11];
  const float* lng = (const float*)d_in[12];
  const float* lnb = (const float*)d_in[13];
  const float* Wp  = (const float*)d_in[14];
  const float* bp  = (const float*)d_in[15];
  const float* lpg = (const float*)d_in[16];
  const float* lpb = (const float*)d_in[17];

  char* ws = (char*)d_ws;
  short* Wqb  = (short*)(ws);                      // [3][256][1024] bf16
  short* Wkb  = (short*)(ws + 1572864ull);
  short* Wvb  = (short*)(ws + 3145728ull);
  short* WoTb = (short*)(ws + 4718592ull);         // [3][256][1024]
  short* WiTb = (short*)(ws + 6291456ull);         // [256][512]
  short* WpTb = (short*)(ws + 6553600ull);         // [256][256]
  short* Wqk  = (short*)(ws + 6684672ull);         // [3][256][256] Bt, pre-scaled 1/16
  short* Wvo  = (short*)(ws + 7077888ull);         // [3][256][256] Bt
  float* cqv  = (float*)(ws + 7471104ull);
  float* ckv  = (float*)(ws + 7474176ull);
  float* cvov = (float*)(ws + 7477248ull);
  float* c0v  = (float*)(ws + 7480320ull);

  { CvP cv;
    cv.src[0]=Wq; cv.dst[0]=Wqb;
    cv.src[1]=Wk; cv.dst[1]=Wkb;
    cv.src[2]=Wv; cv.dst[2]=Wvb;
    cv.src[3]=Wv; cv.dst[3]=Wvb;   // unused slot
    cv.boff[0]=0; cv.boff[1]=384; cv.boff[2]=768; cv.boff[3]=1152; cv.boff[4]=1152;
    k_convert<<<dim3(1152), dim3(256), 0, stream>>>(cv); }

  { TrP tp;
    tp.src[0]=Wi;          tp.dst[0]=WiTb;          tp.rows[0]=512;  tp.cols[0]=256;
    tp.src[1]=Wo;          tp.dst[1]=WoTb;          tp.rows[1]=1024; tp.cols[1]=256;
    tp.src[2]=Wo+262144;   tp.dst[2]=WoTb+262144;   tp.rows[2]=1024; tp.cols[2]=256;
    tp.src[3]=Wo+524288;   tp.dst[3]=WoTb+524288;   tp.rows[3]=1024; tp.cols[3]=256;
    tp.src[4]=Wp;          tp.dst[4]=WpTb;          tp.rows[4]=256;  tp.cols[4]=256;
    tp.toff[0]=0; tp.toff[1]=32; tp.toff[2]=96; tp.toff[3]=160; tp.toff[4]=224; tp.toff[5]=240;
    k_transpose<<<dim3(240), dim3(256), 0, stream>>>(tp); }

  k_vecs2<<<dim3(4, 3), dim3(256), 0, stream>>>(Wqb, Wkb, WoTb, bq, bk, bv, bo,
                                                cqv, ckv, cvov, c0v);

  { GemmP g{};
    for (int l = 0; l < 3; l++){
      g.d[l]   = GDesc{ Wkb  + l*262144, Wqb + l*262144, Wqk + l*65536, 1024, 0.0625f };
      g.d[3+l] = GDesc{ WoTb + l*262144, Wvb + l*262144, Wvo + l*65536, 1024, 1.0f };
    }
    k_gemm128<<<dim3(2,2,6), dim3(256), 0, stream>>>(g); }

  k_net<<<dim3(512), dim3(512), 0, stream>>>(rf, WiTb, bi, emb, Wqk, Wvo,
      ckv, cvov, lng, lnb, WpTb, bp, lpg, lpb, (float*)d_out);
}

// Round 10
// 508.313 us; speedup vs baseline: 1.4081x; 1.1474x over previous
//
#include <hip/hip_runtime.h>
#include <math.h>

// RegionalGNN: B=8192, NC=8, H=256, HD=1024, L=3.
// R10: ONE-LINE FIX of R9. Evidence across R5-R9: __launch_bounds__(512,1)->124 VGPR,
//      (512,4)->64 VGPR. hipcc treats arg2 as CUDA-style min-BLOCKS-per-CU, not
//      waves/EU: (512,4)=32 waves/CU=64-VGPR cap -> R8/R9's ~100 live regs spilled
//      (254-784MB scratch traffic). Now (512,2): 16 waves/CU = 128-VGPR cap, which
//      matches the 77KB-LDS occupancy limit (2 blocks/CU) anyway. No other changes.

typedef short bf16x8 __attribute__((ext_vector_type(8)));
typedef float f32x4  __attribute__((ext_vector_type(4)));

__device__ __forceinline__ float bflo(unsigned int u){ return __uint_as_float(u << 16); }
__device__ __forceinline__ float bfhi(unsigned int u){ return __uint_as_float(u & 0xffff0000u); }
__device__ __forceinline__ float bfs(short s){ return __uint_as_float((unsigned int)(unsigned short)s << 16); }
__device__ __forceinline__ unsigned short f2bf(float f){
  unsigned int u = __float_as_uint(f);
  u += 0x7fffu + ((u >> 16) & 1u);          // RNE
  return (unsigned short)(u >> 16);
}
__device__ __forceinline__ void unpack8(uint4 a, float* o){
  o[0]=bflo(a.x); o[1]=bfhi(a.x); o[2]=bflo(a.y); o[3]=bfhi(a.y);
  o[4]=bflo(a.z); o[5]=bfhi(a.z); o[6]=bflo(a.w); o[7]=bfhi(a.w);
}
__device__ __forceinline__ uint4 pack8(const float* v){
  uint4 r;
  r.x = (unsigned int)f2bf(v[0]) | ((unsigned int)f2bf(v[1]) << 16);
  r.y = (unsigned int)f2bf(v[2]) | ((unsigned int)f2bf(v[3]) << 16);
  r.z = (unsigned int)f2bf(v[4]) | ((unsigned int)f2bf(v[5]) << 16);
  r.w = (unsigned int)f2bf(v[6]) | ((unsigned int)f2bf(v[7]) << 16);
  return r;
}
__device__ __forceinline__ void gload16(const void* g, void* l){
  __builtin_amdgcn_global_load_lds(
      (const __attribute__((address_space(1))) unsigned int*)g,
      (__attribute__((address_space(3))) unsigned int*)l, 16, 0, 0);
}
__device__ __forceinline__ bf16x8 shfl8(bf16x8 v, int src){
  union U { bf16x8 h; int u[4]; };
  U a, r; a.h = v;
  #pragma unroll
  for (int j = 0; j < 4; j++) r.u[j] = __shfl(a.u[j], src);
  return r.h;
}
__device__ __forceinline__ bf16x8 pk8(const float* v){
  bf16x8 r;
  #pragma unroll
  for (int j = 0; j < 8; j++) r[j] = (short)f2bf(v[j]);
  return r;
}

// ---------------- convert f32 -> bf16 (Wq, Wk, Wv) ----------------
struct CvP { const float* src[4]; short* dst[4]; int boff[5]; };
__global__ __launch_bounds__(256) void k_convert(CvP p){
  int bid = blockIdx.x, s = 0;
  while (bid >= p.boff[s+1]) s++;
  size_t e = (size_t)(bid - p.boff[s]) * 2048 + (size_t)threadIdx.x * 8;
  const float* src = p.src[s] + e;
  float4 v0 = *(const float4*)src;
  float4 v1 = *(const float4*)(src + 4);
  float v[8] = {v0.x,v0.y,v0.z,v0.w,v1.x,v1.y,v1.z,v1.w};
  *(uint4*)(p.dst[s] + e) = pack8(v);
}

// ---------------- transpose + convert (Wi, Wo x3, Wp) ----------------
struct TrP { const float* src[5]; short* dst[5]; int rows[5]; int cols[5]; int toff[6]; };
__global__ __launch_bounds__(256) void k_transpose(TrP p){
  __shared__ float tile[64][65];
  int bid = blockIdx.x, s = 0;
  while (bid >= p.toff[s+1]) s++;
  int ti = bid - p.toff[s];
  int cols = p.cols[s], rows = p.rows[s];
  int ntc = cols >> 6;
  int r0 = (ti / ntc) * 64, c0 = (ti % ntc) * 64;
  const float* src = p.src[s];
  int row = threadIdx.x >> 2, jb = (threadIdx.x & 3) * 16;
  #pragma unroll
  for (int j = 0; j < 16; j += 4){
    float4 v = *(const float4*)(src + (size_t)(r0 + row) * cols + c0 + jb + j);
    tile[row][jb+j] = v.x; tile[row][jb+j+1] = v.y; tile[row][jb+j+2] = v.z; tile[row][jb+j+3] = v.w;
  }
  __syncthreads();
  short* dst = p.dst[s];
  float tmp[16];
  #pragma unroll
  for (int j = 0; j < 16; j++) tmp[j] = tile[jb + j][row];
  #pragma unroll
  for (int j = 0; j < 16; j += 8)
    *(uint4*)(dst + (size_t)(c0 + row) * rows + r0 + jb + j) = pack8(&tmp[j]);
}

// ---------------- bias-fold vectors via bf16 row-dots ----------------
__global__ __launch_bounds__(256) void k_vecs2(
    const short* Wqb, const short* Wkb, const short* WoTb,
    const float* bq, const float* bk, const float* bv, const float* bo,
    float* cq, float* ck, float* cvo, float* c0){
  const int job = blockIdx.x, l = blockIdx.y, tid = threadIdx.x;
  __shared__ float sv[1024];
  __shared__ float red[256];
  if (job == 3){
    float pp = 0.f;
    #pragma unroll
    for (int i = 0; i < 4; i++){
      int d = tid*4 + i;
      pp = fmaf(bq[l*1024 + d], bk[l*1024 + d], pp);
    }
    red[tid] = pp; __syncthreads();
    for (int o = 128; o > 0; o >>= 1){ if (tid < o) red[tid] += red[tid + o]; __syncthreads(); }
    if (tid == 0) c0[l] = red[0] * 0.0625f;
    return;
  }
  const short* rows = (job==0 ? Wqb : job==1 ? Wkb : WoTb) + (size_t)l*262144;
  const float* vecg = (job==0 ? bk : job==1 ? bq : bv) + l*1024;
  const float scale = (job == 2) ? 1.0f : 0.0625f;
  for (int i = tid; i < 1024; i += 256) sv[i] = vecg[i];
  __syncthreads();
  const int row = tid >> 3, sub = tid & 7;
  for (int pass = 0; pass < 8; pass++){
    int r = pass*32 + row;
    const short* rp = rows + (size_t)r*1024;
    float acc = 0.f;
    #pragma unroll
    for (int i = 0; i < 16; i++){
      int d = sub*8 + i*64;
      uint4 v = *(const uint4*)(rp + d);
      float f[8]; unpack8(v, f);
      #pragma unroll
      for (int j = 0; j < 8; j++) acc = fmaf(f[j], sv[d + j], acc);
    }
    acc += __shfl_xor(acc, 1); acc += __shfl_xor(acc, 2); acc += __shfl_xor(acc, 4);
    if (sub == 0){
      float o = acc * scale;
      if (job == 2) o += bo[l*256 + r];
      (job==0 ? cq : job==1 ? ck : cvo)[l*256 + r] = o;
    }
  }
}

// ---------------- 128x128 MFMA GEMM (weight precompute only) ----------------
struct GDesc { const short* A; const short* Bt; short* C; int K; float scale; };
struct GemmP { GDesc d[6]; };
__global__ __launch_bounds__(256) void k_gemm128(GemmP p){
  GDesc g = p.d[blockIdx.z];
  const int tid = threadIdx.x, lane = tid & 63, w = tid >> 6;
  const int wm = w >> 1, wn = w & 1;
  __shared__ alignas(16) short As[128*32];
  __shared__ alignas(16) short Bs[128*32];
  const int K = g.K;
  const short* Ab = g.A + (size_t)blockIdx.x * 128 * K;
  const short* Bb = g.Bt + (size_t)blockIdx.y * 128 * K;
  f32x4 acc[4][4] = {};
  for (int k0 = 0; k0 < K; k0 += 32){
    #pragma unroll
    for (int i = 0; i < 2; i++){
      int s = w*2 + i;
      int ro = (s >> 2)*64 + (s & 3)*16 + (lane & 15);
      int co = k0 + (lane >> 4) * 8;
      gload16(Ab + (size_t)ro * K + co, &As[s*512]);
      gload16(Bb + (size_t)ro * K + co, &Bs[s*512]);
    }
    __syncthreads();
    bf16x8 av[4], bv[4];
    #pragma unroll
    for (int mi = 0; mi < 4; mi++)
      av[mi] = *(const bf16x8*)&As[((wm*4 + mi)*64 + lane)*8];
    #pragma unroll
    for (int nj = 0; nj < 4; nj++)
      bv[nj] = *(const bf16x8*)&Bs[((wn*4 + nj)*64 + lane)*8];
    #pragma unroll
    for (int mi = 0; mi < 4; mi++)
      #pragma unroll
      for (int nj = 0; nj < 4; nj++)
        acc[mi][nj] = __builtin_amdgcn_mfma_f32_16x16x32_bf16(av[mi], bv[nj], acc[mi][nj], 0, 0, 0);
    __syncthreads();
  }
  const int ldc = gridDim.y * 128;
  #pragma unroll
  for (int mi = 0; mi < 4; mi++)
    #pragma unroll
    for (int nj = 0; nj < 4; nj++){
      int rm0 = blockIdx.x*128 + wm*64 + mi*16 + (lane >> 4) * 4;
      int cn  = blockIdx.y*128 + wn*64 + nj*16 + (lane & 15);
      #pragma unroll
      for (int j = 0; j < 4; j++)
        g.C[(size_t)(rm0 + j) * ldc + cn] = (short)f2bf(acc[mi][nj][j] * g.scale);
    }
}

// ---------------- mega-kernel: whole network, X in registers (one layout) ----------------
// Block = 16 batches (128 X-rows). Wave = batch-pair (16 rows, lane&15 = row).
// xf: A-frag layout, element (r,d) at lane(r + 16*((d&31)>>3)), chunk c=d>>5, elem d&7.
// Stash addr of (r,d) in tst[w]: (d>>5)*512 + (r + 16*((d>>3)&3))*8 + (d&7).
__global__ __launch_bounds__(512, 2) void k_net(
    const float* __restrict__ rf, const short* __restrict__ WiT,
    const float* __restrict__ bi, const float* __restrict__ emb,
    const short* __restrict__ Wqk, const short* __restrict__ Wvo,
    const float* __restrict__ ckv, const float* __restrict__ cvov,
    const float* __restrict__ lng, const float* __restrict__ lnb,
    const short* __restrict__ WpT, const float* __restrict__ bpv,
    const float* __restrict__ lpg, const float* __restrict__ lpb,
    float* __restrict__ outp){
  const int tid = threadIdx.x, lane = tid & 63, w = tid >> 6;
  const int b0 = blockIdx.x * 16;
  const int dsub = (lane >> 4) * 8;
  __shared__ alignas(16) short tst[8][4096];     // 64 KB: per-wave 8KB stash
  __shared__ alignas(16) float atn[8][16][16];   // 8 KB: attn probs / LN stats
  __shared__ short ckb[256];
  __shared__ float s_add[256], s_g[256], s_b[256];
  __shared__ float redS[8][16], redQ[8][16], s_mean[16], s_rstd[16];

  #define LKW asm volatile("s_waitcnt lgkmcnt(0)" ::: "memory")

  // ===== input projection: h = rf@Wi + bi (per-wave N-slice, B direct-global) =====
  float* hst  = (float*)&tst[0][0];   // [16][264] f32
  float* embs = hst + 16*264;         // [8][256]  f32
  float* bis  = embs + 2048;          // [256]     f32
  if (tid < 256) bis[tid] = bi[tid];
  for (int i = tid; i < 2048; i += 512) embs[i] = emb[i];
  f32x4 hacc[2] = {};
  #pragma unroll
  for (int kk = 0; kk < 16; kk++){
    const float* ap = rf + (size_t)(b0 + (lane & 15)) * 512 + kk*32 + dsub;
    float4 a0 = *(const float4*)ap, a1 = *(const float4*)(ap + 4);
    float af[8] = {a0.x,a0.y,a0.z,a0.w,a1.x,a1.y,a1.z,a1.w};
    bf16x8 av = pk8(af);
    #pragma unroll
    for (int nj = 0; nj < 2; nj++){
      bf16x8 bv = *(const bf16x8*)(WiT + (size_t)(w*32 + nj*16 + (lane & 15))*512 + kk*32 + dsub);
      hacc[nj] = __builtin_amdgcn_mfma_f32_16x16x32_bf16(av, bv, hacc[nj], 0, 0, 0);
    }
  }
  __syncthreads();   // bis/embs published
  #pragma unroll
  for (int nj = 0; nj < 2; nj++)
    #pragma unroll
    for (int jj = 0; jj < 4; jj++){
      int m = (lane >> 4)*4 + jj, col = w*32 + nj*16 + (lane & 15);
      hst[m*264 + col] = hacc[nj][jj] + bis[col];
    }
  __syncthreads();   // hst published
  // build xf (A-layout) = bf16(h + bi + emb)
  bf16x8 xf[8];
  {
    int r15 = lane & 15;
    int bt = w*2 + (r15 >> 3), ct = r15 & 7;
    #pragma unroll
    for (int c = 0; c < 8; c++){
      float v8[8];
      #pragma unroll
      for (int e = 0; e < 8; e++){
        int d = dsub + 32*c + e;
        v8[e] = hst[bt*264 + d] + embs[ct*256 + d];
      }
      xf[c] = pk8(v8);
    }
  }

  const unsigned long long MASK64 = 0x02191D69752B857EULL;   // ADJ[n][m] at bit n*8+m

  // ===== layers =====
  #pragma unroll 1
  for (int l = 0; l < 3; ++l){
    __syncthreads();   // protect hst readers (l==0) / prev-layer s_* readers
    if (tid < 256){
      ckb[tid]   = (short)f2bf(ckv[l*256 + tid]);
      s_add[tid] = cvov[l*256 + tid];
      s_g[tid]   = lng[l*256 + tid];
      s_b[tid]   = lnb[l*256 + tid];
    }
    const short* Wq_ = Wqk + l*65536;
    const short* Wv_ = Wvo + l*65536;
    __syncthreads();   // publish

    // ---- GEMM1: T = X @ Wqk (B direct-global); scores via stash-MFMA ----
    f32x4 sacc = {0.f, 0.f, 0.f, 0.f};
    #pragma unroll
    for (int h = 0; h < 2; h++){
      f32x4 acc[8] = {};
      #pragma unroll
      for (int kk = 0; kk < 8; kk++)
        #pragma unroll
        for (int nj = 0; nj < 8; nj++){
          bf16x8 bv = *(const bf16x8*)(Wq_ + (size_t)(h*128 + nj*16 + (lane & 15))*256 + kk*32 + dsub);
          acc[nj] = __builtin_amdgcn_mfma_f32_16x16x32_bf16(xf[kk], bv, acc[nj], 0, 0, 0);
        }
      #pragma unroll
      for (int nj = 0; nj < 8; nj++)
        #pragma unroll
        for (int jj = 0; jj < 4; jj++){
          int i_ = (lane >> 4)*4 + jj, nl = nj*16 + (lane & 15);
          tst[w][(nl >> 5)*512 + (i_ + 16*((nl >> 3) & 3))*8 + (nl & 7)] = (short)f2bf(acc[nj][jj]);
        }
      LKW; __builtin_amdgcn_sched_barrier(0);
      #pragma unroll
      for (int cl = 0; cl < 4; cl++){
        bf16x8 tf = *(const bf16x8*)&tst[w][cl*512 + lane*8];
        sacc = __builtin_amdgcn_mfma_f32_16x16x32_bf16(tf, xf[h*4 + cl], sacc, 0, 0, 0);
      }
      LKW;   // reads drained before next-half overwrite
    }

    // ---- skv[m] = X[m].ck ----
    float skv = 0.f;
    #pragma unroll
    for (int c = 0; c < 8; c++){
      bf16x8 cv = *(const bf16x8*)&ckb[c*32 + dsub];
      #pragma unroll
      for (int e = 0; e < 8; e++) skv = fmaf(bfs(xf[c][e]), bfs(cv[e]), skv);
    }
    skv += __shfl_xor(skv, 16); skv += __shfl_xor(skv, 32);

    // ---- softmax (C-layout) -> atn[w] ----
    #pragma unroll
    for (int jj = 0; jj < 4; jj++){
      int i_ = (lane >> 4)*4 + jj, j_ = lane & 15;
      bool ok = (((i_ ^ j_) & 8) == 0) &&
                ((MASK64 >> (((i_ & 7) << 3) | (j_ & 7))) & 1ull);
      float sv = ok ? (sacc[jj] + skv) : -3.0e38f;
      float mx = sv;
      mx = fmaxf(mx, __shfl_xor(mx, 1));
      mx = fmaxf(mx, __shfl_xor(mx, 2));
      mx = fmaxf(mx, __shfl_xor(mx, 4));
      float e = ok ? __expf(sv - mx) : 0.f;
      float sum = e;
      sum += __shfl_xor(sum, 1); sum += __shfl_xor(sum, 2); sum += __shfl_xor(sum, 4);
      atn[w][i_][j_] = e / sum;
    }
    LKW;   // own-wave atn writes -> reads

    // ---- PV: yfrag (A-layout) via shfl from xf ----
    bf16x8 yfrag[8];
    {
      float4 A0 = *(const float4*)&atn[w][lane & 15][lane & 8];
      float4 A1 = *(const float4*)&atn[w][lane & 15][(lane & 8) + 4];
      float am[8] = {A0.x, A0.y, A0.z, A0.w, A1.x, A1.y, A1.z, A1.w};
      #pragma unroll
      for (int c = 0; c < 8; c++){
        float a8[8] = {0,0,0,0,0,0,0,0};
        #pragma unroll
        for (int mi = 0; mi < 8; mi++){
          bf16x8 xs = shfl8(xf[c], (lane & 48) | (lane & 8) | mi);
          #pragma unroll
          for (int e = 0; e < 8; e++) a8[e] = fmaf(am[mi], bfs(xs[e]), a8[e]);
        }
        yfrag[c] = pk8(a8);
      }
    }

    // ---- stash X (A-layout, contiguous b128) -> tst[w]; xf dead until LN-apply ----
    #pragma unroll
    for (int c = 0; c < 8; c++)
      *(bf16x8*)&tst[w][c*512 + lane*8] = xf[c];
    LKW; __builtin_amdgcn_sched_barrier(0);

    // ---- GEMM2 + epilogue per half: t = acc + cvo + X_res (from stash, C-layout) ----
    float rs[4] = {0,0,0,0}, rq[4] = {0,0,0,0};
    #pragma unroll
    for (int h = 0; h < 2; h++){
      f32x4 acc[8] = {};
      #pragma unroll
      for (int kk = 0; kk < 8; kk++)
        #pragma unroll
        for (int nj = 0; nj < 8; nj++){
          bf16x8 bv = *(const bf16x8*)(Wv_ + (size_t)(h*128 + nj*16 + (lane & 15))*256 + kk*32 + dsub);
          acc[nj] = __builtin_amdgcn_mfma_f32_16x16x32_bf16(yfrag[kk], bv, acc[nj], 0, 0, 0);
        }
      #pragma unroll
      for (int nj = 0; nj < 8; nj++){
        int n = h*128 + nj*16 + (lane & 15);
        float sadd = s_add[n];
        #pragma unroll
        for (int jj = 0; jj < 4; jj++){
          int i_ = (lane >> 4)*4 + jj;
          int ad = (n >> 5)*512 + (i_ + 16*((n >> 3) & 3))*8 + (n & 7);
          float t = acc[nj][jj] + sadd + bfs(tst[w][ad]);   // RAW same-lane: dep-ordered
          rs[jj] += t; rq[jj] = fmaf(t, t, rq[jj]);
          tst[w][ad] = (short)f2bf(t);                      // overwrite X slot with t
        }
      }
    }
    // ---- LN stats -> atn[w] scratch (attn probs dead) ----
    float* stp = &atn[w][0][0];
    #pragma unroll
    for (int jj = 0; jj < 4; jj++){
      float s = rs[jj], q = rq[jj];
      s += __shfl_xor(s, 1); q += __shfl_xor(q, 1);
      s += __shfl_xor(s, 2); q += __shfl_xor(q, 2);
      s += __shfl_xor(s, 4); q += __shfl_xor(q, 4);
      s += __shfl_xor(s, 8); q += __shfl_xor(q, 8);
      if ((lane & 15) == 0){
        int i_ = (lane >> 4)*4 + jj;
        float mn = s * (1.f/256.f);
        float var = q * (1.f/256.f) - mn*mn;
        stp[i_]      = mn;
        stp[16 + i_] = rsqrtf(fmaxf(var, 0.f) + 1e-5f);
      }
    }
    LKW; __builtin_amdgcn_sched_barrier(0);   // t-writes + stp visible within wave
    // ---- LN apply: read t (A-layout contiguous), row stats = row lane&15 ----
    {
      float mn = stp[lane & 15], rr = stp[16 + (lane & 15)];
      #pragma unroll
      for (int c = 0; c < 8; c++){
        bf16x8 tv = *(const bf16x8*)&tst[w][c*512 + lane*8];
        float v8[8];
        #pragma unroll
        for (int e = 0; e < 8; e++){
          int d = c*32 + dsub + e;
          v8[e] = (bfs(tv[e]) - mn) * rr * s_g[d] + s_b[d];
        }
        xf[c] = pk8(v8);
      }
    }
    LKW;   // stash reads drained before next layer reuses tst[w]
  } // layers

  // ===== head: GDP-reduce -> Astage -> GEMM vs WpT -> LN -> GELU =====
  __syncthreads();   // tst becomes cross-wave Astage
  short* Ast = &tst[0][0];   // [16][264] bf16
  {
    int c7 = lane & 7;
    float g = (c7 == 0) ? 0.4f : (c7 == 1) ? 0.15f : (c7 == 2) ? 0.12f :
              (c7 == 3) ? 0.1f : (c7 == 4) ? 0.08f : (c7 == 5) ? 0.08f :
              (c7 == 6) ? 0.05f : 0.02f;
    #pragma unroll
    for (int c = 0; c < 8; c++){
      float v8[8];
      #pragma unroll
      for (int e = 0; e < 8; e++){
        float v = g * bfs(xf[c][e]);
        v += __shfl_xor(v, 1); v += __shfl_xor(v, 2); v += __shfl_xor(v, 4);
        v8[e] = v;
      }
      if ((lane & 7) == 0){
        int bt = w*2 + ((lane >> 3) & 1);
        *(bf16x8*)&Ast[bt*264 + dsub + 32*c] = pk8(v8);
      }
    }
  }
  __syncthreads();
  f32x4 ha[2] = {};
  #pragma unroll
  for (int kk = 0; kk < 8; kk++){
    bf16x8 av = *(const bf16x8*)&Ast[(lane & 15)*264 + kk*32 + dsub];
    #pragma unroll
    for (int nj = 0; nj < 2; nj++){
      bf16x8 bv = *(const bf16x8*)(WpT + (size_t)(w*32 + nj*16 + (lane & 15))*256 + kk*32 + dsub);
      ha[nj] = __builtin_amdgcn_mfma_f32_16x16x32_bf16(av, bv, ha[nj], 0, 0, 0);
    }
  }
  #pragma unroll
  for (int jj = 0; jj < 4; jj++){
    float s = 0.f, q = 0.f;
    #pragma unroll
    for (int nj = 0; nj < 2; nj++){
      int cx = w*32 + nj*16 + (lane & 15);
      float t = ha[nj][jj] + bpv[cx];
      ha[nj][jj] = t;
      s += t; q = fmaf(t, t, q);
    }
    s += __shfl_xor(s, 1); q += __shfl_xor(q, 1);
    s += __shfl_xor(s, 2); q += __shfl_xor(q, 2);
    s += __shfl_xor(s, 4); q += __shfl_xor(q, 4);
    s += __shfl_xor(s, 8); q += __shfl_xor(q, 8);
    if ((lane & 15) == 0){
      int rl = (lane >> 4)*4 + jj;
      redS[w][rl] = s; redQ[w][rl] = q;
    }
  }
  __syncthreads();
  if (tid < 16){
    float sm = 0.f, sq = 0.f;
    #pragma unroll
    for (int w2 = 0; w2 < 8; w2++){ sm += redS[w2][tid]; sq += redQ[w2][tid]; }
    float mn = sm * (1.f/256.f);
    float var = sq * (1.f/256.f) - mn*mn;
    s_mean[tid] = mn;
    s_rstd[tid] = rsqrtf(fmaxf(var, 0.f) + 1e-5f);
  }
  __syncthreads();
  #pragma unroll
  for (int jj = 0; jj < 4; jj++){
    int rl = (lane >> 4)*4 + jj;
    float mn = s_mean[rl], rstd = s_rstd[rl];
    #pragma unroll
    for (int nj = 0; nj < 2; nj++){
      int cx = w*32 + nj*16 + (lane & 15);
      float y = (ha[nj][jj] - mn) * rstd * lpg[cx] + lpb[cx];
      outp[(size_t)(b0 + rl)*256 + cx] = 0.5f * y * (1.0f + erff(y * 0.70710678118654752f));
    }
  }
  #undef LKW
}

extern "C" void kernel_launch(void* const* d_in, const int* in_sizes, int n_in,
                              void* d_out, int out_size, void* d_ws, size_t ws_size,
                              hipStream_t stream){
  (void)in_sizes; (void)n_in; (void)out_size; (void)ws_size;
  const float* rf  = (const float*)d_in[0];
  const float* Wi  = (const float*)d_in[1];
  const float* bi  = (const float*)d_in[2];
  const float* emb = (const float*)d_in[3];
  const float* Wq  = (const float*)d_in[4];
  const float* bq  = (const float*)d_in[5];
  const float* Wk  = (const float*)d_in[6];
  const float* bk  = (const float*)d_in[7];
  const float* Wv  = (const float*)d_in[8];
  const float* bv  = (const float*)d_in[9];
  const float* Wo  = (const float*)d_in[10];
  const float* bo  = (const float*)d_in[11];
  const float* lng = (const float*)d_in[12];
  const float* lnb = (const float*)d_in[13];
  const float* Wp  = (const float*)d_in[14];
  const float* bp  = (const float*)d_in[15];
  const float* lpg = (const float*)d_in[16];
  const float* lpb = (const float*)d_in[17];

  char* ws = (char*)d_ws;
  short* Wqb  = (short*)(ws);                      // [3][256][1024] bf16
  short* Wkb  = (short*)(ws + 1572864ull);
  short* Wvb  = (short*)(ws + 3145728ull);
  short* WoTb = (short*)(ws + 4718592ull);         // [3][256][1024]
  short* WiTb = (short*)(ws + 6291456ull);         // [256][512]
  short* WpTb = (short*)(ws + 6553600ull);         // [256][256]
  short* Wqk  = (short*)(ws + 6684672ull);         // [3][256][256] Bt, pre-scaled 1/16
  short* Wvo  = (short*)(ws + 7077888ull);         // [3][256][256] Bt
  float* cqv  = (float*)(ws + 7471104ull);
  float* ckv  = (float*)(ws + 7474176ull);
  float* cvov = (float*)(ws + 7477248ull);
  float* c0v  = (float*)(ws + 7480320ull);

  { CvP cv;
    cv.src[0]=Wq; cv.dst[0]=Wqb;
    cv.src[1]=Wk; cv.dst[1]=Wkb;
    cv.src[2]=Wv; cv.dst[2]=Wvb;
    cv.src[3]=Wv; cv.dst[3]=Wvb;   // unused slot
    cv.boff[0]=0; cv.boff[1]=384; cv.boff[2]=768; cv.boff[3]=1152; cv.boff[4]=1152;
    k_convert<<<dim3(1152), dim3(256), 0, stream>>>(cv); }

  { TrP tp;
    tp.src[0]=Wi;          tp.dst[0]=WiTb;          tp.rows[0]=512;  tp.cols[0]=256;
    tp.src[1]=Wo;          tp.dst[1]=WoTb;          tp.rows[1]=1024; tp.cols[1]=256;
    tp.src[2]=Wo+262144;   tp.dst[2]=WoTb+262144;   tp.rows[2]=1024; tp.cols[2]=256;
    tp.src[3]=Wo+524288;   tp.dst[3]=WoTb+524288;   tp.rows[3]=1024; tp.cols[3]=256;
    tp.src[4]=Wp;          tp.dst[4]=WpTb;          tp.rows[4]=256;  tp.cols[4]=256;
    tp.toff[0]=0; tp.toff[1]=32; tp.toff[2]=96; tp.toff[3]=160; tp.toff[4]=224; tp.toff[5]=240;
    k_transpose<<<dim3(240), dim3(256), 0, stream>>>(tp); }

  k_vecs2<<<dim3(4, 3), dim3(256), 0, stream>>>(Wqb, Wkb, WoTb, bq, bk, bv, bo,
                                                cqv, ckv, cvov, c0v);

  { GemmP g{};
    for (int l = 0; l < 3; l++){
      g.d[l]   = GDesc{ Wkb  + l*262144, Wqb + l*262144, Wqk + l*65536, 1024, 0.0625f };
      g.d[3+l] = GDesc{ WoTb + l*262144, Wvb + l*262144, Wvo + l*65536, 1024, 1.0f };
    }
    k_gemm128<<<dim3(2,2,6), dim3(256), 0, stream>>>(g); }

  k_net<<<dim3(512), dim3(512), 0, stream>>>(rf, WiTb, bi, emb, Wqk, Wvo,
      ckv, cvov, lng, lnb, WpTb, bp, lpg, lpb, (float*)d_out);
}

// Round 11
// 271.618 us; speedup vs baseline: 2.6352x; 1.8714x over previous
//
#include <hip/hip_runtime.h>
#include <math.h>

// RegionalGNN: B=8192, NC=8, H=256, HD=1024, L=3.
// R11: weight FRAG-PACKING. R10 diagnosis: k_net latency-bound on L2 scatter
//      queueing -- each per-lane B-frag load touches 16 cache lines (16 rows x
//      512B stride); 4096 waves x 830 loads -> ~5K-cycle L2 latency, ~8-deep MLP.
//      Fix: pre-pack Wqk/Wvo/WiT/WpT into frag-major order (k_repack, one-shot)
//      so every B-load is ONE contiguous 1KB segment. Same values per lane ->
//      numerically identical. k_net structure unchanged from R10 (VGPR 116, no spill).

typedef short bf16x8 __attribute__((ext_vector_type(8)));
typedef float f32x4  __attribute__((ext_vector_type(4)));

__device__ __forceinline__ float bflo(unsigned int u){ return __uint_as_float(u << 16); }
__device__ __forceinline__ float bfhi(unsigned int u){ return __uint_as_float(u & 0xffff0000u); }
__device__ __forceinline__ float bfs(short s){ return __uint_as_float((unsigned int)(unsigned short)s << 16); }
__device__ __forceinline__ unsigned short f2bf(float f){
  unsigned int u = __float_as_uint(f);
  u += 0x7fffu + ((u >> 16) & 1u);          // RNE
  return (unsigned short)(u >> 16);
}
__device__ __forceinline__ void unpack8(uint4 a, float* o){
  o[0]=bflo(a.x); o[1]=bfhi(a.x); o[2]=bflo(a.y); o[3]=bfhi(a.y);
  o[4]=bflo(a.z); o[5]=bfhi(a.z); o[6]=bflo(a.w); o[7]=bfhi(a.w);
}
__device__ __forceinline__ uint4 pack8(const float* v){
  uint4 r;
  r.x = (unsigned int)f2bf(v[0]) | ((unsigned int)f2bf(v[1]) << 16);
  r.y = (unsigned int)f2bf(v[2]) | ((unsigned int)f2bf(v[3]) << 16);
  r.z = (unsigned int)f2bf(v[4]) | ((unsigned int)f2bf(v[5]) << 16);
  r.w = (unsigned int)f2bf(v[6]) | ((unsigned int)f2bf(v[7]) << 16);
  return r;
}
__device__ __forceinline__ void gload16(const void* g, void* l){
  __builtin_amdgcn_global_load_lds(
      (const __attribute__((address_space(1))) unsigned int*)g,
      (__attribute__((address_space(3))) unsigned int*)l, 16, 0, 0);
}
__device__ __forceinline__ bf16x8 shfl8(bf16x8 v, int src){
  union U { bf16x8 h; int u[4]; };
  U a, r; a.h = v;
  #pragma unroll
  for (int j = 0; j < 4; j++) r.u[j] = __shfl(a.u[j], src);
  return r.h;
}
__device__ __forceinline__ bf16x8 pk8(const float* v){
  bf16x8 r;
  #pragma unroll
  for (int j = 0; j < 8; j++) r[j] = (short)f2bf(v[j]);
  return r;
}

// ---------------- convert f32 -> bf16 (Wq, Wk, Wv) ----------------
struct CvP { const float* src[4]; short* dst[4]; int boff[5]; };
__global__ __launch_bounds__(256) void k_convert(CvP p){
  int bid = blockIdx.x, s = 0;
  while (bid >= p.boff[s+1]) s++;
  size_t e = (size_t)(bid - p.boff[s]) * 2048 + (size_t)threadIdx.x * 8;
  const float* src = p.src[s] + e;
  float4 v0 = *(const float4*)src;
  float4 v1 = *(const float4*)(src + 4);
  float v[8] = {v0.x,v0.y,v0.z,v0.w,v1.x,v1.y,v1.z,v1.w};
  *(uint4*)(p.dst[s] + e) = pack8(v);
}

// ---------------- transpose + convert (Wi, Wo x3, Wp) ----------------
struct TrP { const float* src[5]; short* dst[5]; int rows[5]; int cols[5]; int toff[6]; };
__global__ __launch_bounds__(256) void k_transpose(TrP p){
  __shared__ float tile[64][65];
  int bid = blockIdx.x, s = 0;
  while (bid >= p.toff[s+1]) s++;
  int ti = bid - p.toff[s];
  int cols = p.cols[s], rows = p.rows[s];
  int ntc = cols >> 6;
  int r0 = (ti / ntc) * 64, c0 = (ti % ntc) * 64;
  const float* src = p.src[s];
  int row = threadIdx.x >> 2, jb = (threadIdx.x & 3) * 16;
  #pragma unroll
  for (int j = 0; j < 16; j += 4){
    float4 v = *(const float4*)(src + (size_t)(r0 + row) * cols + c0 + jb + j);
    tile[row][jb+j] = v.x; tile[row][jb+j+1] = v.y; tile[row][jb+j+2] = v.z; tile[row][jb+j+3] = v.w;
  }
  __syncthreads();
  short* dst = p.dst[s];
  float tmp[16];
  #pragma unroll
  for (int j = 0; j < 16; j++) tmp[j] = tile[jb + j][row];
  #pragma unroll
  for (int j = 0; j < 16; j += 8)
    *(uint4*)(dst + (size_t)(c0 + row) * rows + r0 + jb + j) = pack8(&tmp[j]);
}

// ---------------- bias-fold vectors via bf16 row-dots ----------------
__global__ __launch_bounds__(256) void k_vecs2(
    const short* Wqb, const short* Wkb, const short* WoTb,
    const float* bq, const float* bk, const float* bv, const float* bo,
    float* cq, float* ck, float* cvo, float* c0){
  const int job = blockIdx.x, l = blockIdx.y, tid = threadIdx.x;
  __shared__ float sv[1024];
  __shared__ float red[256];
  if (job == 3){
    float pp = 0.f;
    #pragma unroll
    for (int i = 0; i < 4; i++){
      int d = tid*4 + i;
      pp = fmaf(bq[l*1024 + d], bk[l*1024 + d], pp);
    }
    red[tid] = pp; __syncthreads();
    for (int o = 128; o > 0; o >>= 1){ if (tid < o) red[tid] += red[tid + o]; __syncthreads(); }
    if (tid == 0) c0[l] = red[0] * 0.0625f;
    return;
  }
  const short* rows = (job==0 ? Wqb : job==1 ? Wkb : WoTb) + (size_t)l*262144;
  const float* vecg = (job==0 ? bk : job==1 ? bq : bv) + l*1024;
  const float scale = (job == 2) ? 1.0f : 0.0625f;
  for (int i = tid; i < 1024; i += 256) sv[i] = vecg[i];
  __syncthreads();
  const int row = tid >> 3, sub = tid & 7;
  for (int pass = 0; pass < 8; pass++){
    int r = pass*32 + row;
    const short* rp = rows + (size_t)r*1024;
    float acc = 0.f;
    #pragma unroll
    for (int i = 0; i < 16; i++){
      int d = sub*8 + i*64;
      uint4 v = *(const uint4*)(rp + d);
      float f[8]; unpack8(v, f);
      #pragma unroll
      for (int j = 0; j < 8; j++) acc = fmaf(f[j], sv[d + j], acc);
    }
    acc += __shfl_xor(acc, 1); acc += __shfl_xor(acc, 2); acc += __shfl_xor(acc, 4);
    if (sub == 0){
      float o = acc * scale;
      if (job == 2) o += bo[l*256 + r];
      (job==0 ? cq : job==1 ? ck : cvo)[l*256 + r] = o;
    }
  }
}

// ---------------- 128x128 MFMA GEMM (weight precompute only) ----------------
struct GDesc { const short* A; const short* Bt; short* C; int K; float scale; };
struct GemmP { GDesc d[6]; };
__global__ __launch_bounds__(256) void k_gemm128(GemmP p){
  GDesc g = p.d[blockIdx.z];
  const int tid = threadIdx.x, lane = tid & 63, w = tid >> 6;
  const int wm = w >> 1, wn = w & 1;
  __shared__ alignas(16) short As[128*32];
  __shared__ alignas(16) short Bs[128*32];
  const int K = g.K;
  const short* Ab = g.A + (size_t)blockIdx.x * 128 * K;
  const short* Bb = g.Bt + (size_t)blockIdx.y * 128 * K;
  f32x4 acc[4][4] = {};
  for (int k0 = 0; k0 < K; k0 += 32){
    #pragma unroll
    for (int i = 0; i < 2; i++){
      int s = w*2 + i;
      int ro = (s >> 2)*64 + (s & 3)*16 + (lane & 15);
      int co = k0 + (lane >> 4) * 8;
      gload16(Ab + (size_t)ro * K + co, &As[s*512]);
      gload16(Bb + (size_t)ro * K + co, &Bs[s*512]);
    }
    __syncthreads();
    bf16x8 av[4], bv[4];
    #pragma unroll
    for (int mi = 0; mi < 4; mi++)
      av[mi] = *(const bf16x8*)&As[((wm*4 + mi)*64 + lane)*8];
    #pragma unroll
    for (int nj = 0; nj < 4; nj++)
      bv[nj] = *(const bf16x8*)&Bs[((wn*4 + nj)*64 + lane)*8];
    #pragma unroll
    for (int mi = 0; mi < 4; mi++)
      #pragma unroll
      for (int nj = 0; nj < 4; nj++)
        acc[mi][nj] = __builtin_amdgcn_mfma_f32_16x16x32_bf16(av[mi], bv[nj], acc[mi][nj], 0, 0, 0);
    __syncthreads();
  }
  const int ldc = gridDim.y * 128;
  #pragma unroll
  for (int mi = 0; mi < 4; mi++)
    #pragma unroll
    for (int nj = 0; nj < 4; nj++){
      int rm0 = blockIdx.x*128 + wm*64 + mi*16 + (lane >> 4) * 4;
      int cn  = blockIdx.y*128 + wn*64 + nj*16 + (lane & 15);
      #pragma unroll
      for (int j = 0; j < 4; j++)
        g.C[(size_t)(rm0 + j) * ldc + cn] = (short)f2bf(acc[mi][nj][j] * g.scale);
    }
}

// ---------------- frag-pack repack: row-major [N][K] -> [(K/32)*16][512] ----------------
// packed[((k>>5)*16 + (n>>4))*512 + ((n&15) + 16*((k>>3)&3))*8 + (k&7)] = src[n*K + k]
struct RpP { const short* src[8]; short* dst[8]; int K[8]; int boff[9]; };
__global__ __launch_bounds__(256) void k_repack(RpP p){
  int bid = blockIdx.x, s = 0;
  while (bid >= p.boff[s+1]) s++;
  int kk = bid - p.boff[s];
  const short* src = p.src[s];
  short* dst = p.dst[s] + (size_t)kk * 8192;
  int K = p.K[s];
  int r15 = threadIdx.x & 15, nt = threadIdx.x >> 4;
  const short* sp = src + (size_t)(nt*16 + r15) * K + kk*32;
  short* dp = dst + nt*512 + r15*8;
  #pragma unroll
  for (int q = 0; q < 4; q++)
    *(uint4*)(dp + q*128) = *(const uint4*)(sp + q*8);
}

// ---------------- mega-kernel: whole network, X in registers (one layout) ----------------
// Block = 16 batches (128 X-rows). Wave = batch-pair (16 rows, lane&15 = row).
// xf: A-frag layout. Stash addr of (r,d) in tst[w]: (d>>5)*512 + (r + 16*((d>>3)&3))*8 + (d&7).
// All weight B-frags come from FRAG-PACKED arrays: one contiguous 1KB load per (kk,nj).
__global__ __launch_bounds__(512, 2) void k_net(
    const float* __restrict__ rf, const short* __restrict__ WiT,
    const float* __restrict__ bi, const float* __restrict__ emb,
    const short* __restrict__ Wqk, const short* __restrict__ Wvo,
    const float* __restrict__ ckv, const float* __restrict__ cvov,
    const float* __restrict__ lng, const float* __restrict__ lnb,
    const short* __restrict__ WpT, const float* __restrict__ bpv,
    const float* __restrict__ lpg, const float* __restrict__ lpb,
    float* __restrict__ outp){
  const int tid = threadIdx.x, lane = tid & 63, w = tid >> 6;
  const int b0 = blockIdx.x * 16;
  const int dsub = (lane >> 4) * 8;
  __shared__ alignas(16) short tst[8][4096];     // 64 KB: per-wave 8KB stash
  __shared__ alignas(16) float atn[8][16][16];   // 8 KB: attn probs / LN stats
  __shared__ short ckb[256];
  __shared__ float s_add[256], s_g[256], s_b[256];
  __shared__ float redS[8][16], redQ[8][16], s_mean[16], s_rstd[16];

  #define LKW asm volatile("s_waitcnt lgkmcnt(0)" ::: "memory")

  // ===== input projection: h = rf@Wi + bi (B from frag-packed WiT) =====
  float* hst  = (float*)&tst[0][0];   // [16][264] f32
  float* embs = hst + 16*264;         // [8][256]  f32
  float* bis  = embs + 2048;          // [256]     f32
  if (tid < 256) bis[tid] = bi[tid];
  for (int i = tid; i < 2048; i += 512) embs[i] = emb[i];
  f32x4 hacc[2] = {};
  #pragma unroll
  for (int kk = 0; kk < 16; kk++){
    const float* ap = rf + (size_t)(b0 + (lane & 15)) * 512 + kk*32 + dsub;
    float4 a0 = *(const float4*)ap, a1 = *(const float4*)(ap + 4);
    float af[8] = {a0.x,a0.y,a0.z,a0.w,a1.x,a1.y,a1.z,a1.w};
    bf16x8 av = pk8(af);
    #pragma unroll
    for (int nj = 0; nj < 2; nj++){
      bf16x8 bv = *(const bf16x8*)(WiT + (size_t)(kk*16 + w*2 + nj)*512 + lane*8);
      hacc[nj] = __builtin_amdgcn_mfma_f32_16x16x32_bf16(av, bv, hacc[nj], 0, 0, 0);
    }
  }
  __syncthreads();   // bis/embs published
  #pragma unroll
  for (int nj = 0; nj < 2; nj++)
    #pragma unroll
    for (int jj = 0; jj < 4; jj++){
      int m = (lane >> 4)*4 + jj, col = w*32 + nj*16 + (lane & 15);
      hst[m*264 + col] = hacc[nj][jj] + bis[col];
    }
  __syncthreads();   // hst published
  // build xf (A-layout) = bf16(h + bi + emb)
  bf16x8 xf[8];
  {
    int r15 = lane & 15;
    int bt = w*2 + (r15 >> 3), ct = r15 & 7;
    #pragma unroll
    for (int c = 0; c < 8; c++){
      float v8[8];
      #pragma unroll
      for (int e = 0; e < 8; e++){
        int d = dsub + 32*c + e;
        v8[e] = hst[bt*264 + d] + embs[ct*256 + d];
      }
      xf[c] = pk8(v8);
    }
  }

  const unsigned long long MASK64 = 0x02191D69752B857EULL;   // ADJ[n][m] at bit n*8+m

  // ===== layers =====
  #pragma unroll 1
  for (int l = 0; l < 3; ++l){
    __syncthreads();   // protect hst readers (l==0) / prev-layer s_* readers
    if (tid < 256){
      ckb[tid]   = (short)f2bf(ckv[l*256 + tid]);
      s_add[tid] = cvov[l*256 + tid];
      s_g[tid]   = lng[l*256 + tid];
      s_b[tid]   = lnb[l*256 + tid];
    }
    const short* Wq_ = Wqk + l*65536;   // frag-packed [8 kk][16 ntile][512]
    const short* Wv_ = Wvo + l*65536;
    __syncthreads();   // publish

    // ---- GEMM1: T = X @ Wqk (B frag-packed); scores via stash-MFMA ----
    f32x4 sacc = {0.f, 0.f, 0.f, 0.f};
    #pragma unroll
    for (int h = 0; h < 2; h++){
      f32x4 acc[8] = {};
      #pragma unroll
      for (int kk = 0; kk < 8; kk++)
        #pragma unroll
        for (int nj = 0; nj < 8; nj++){
          bf16x8 bv = *(const bf16x8*)(Wq_ + (size_t)(kk*16 + h*8 + nj)*512 + lane*8);
          acc[nj] = __builtin_amdgcn_mfma_f32_16x16x32_bf16(xf[kk], bv, acc[nj], 0, 0, 0);
        }
      #pragma unroll
      for (int nj = 0; nj < 8; nj++)
        #pragma unroll
        for (int jj = 0; jj < 4; jj++){
          int i_ = (lane >> 4)*4 + jj, nl = nj*16 + (lane & 15);
          tst[w][(nl >> 5)*512 + (i_ + 16*((nl >> 3) & 3))*8 + (nl & 7)] = (short)f2bf(acc[nj][jj]);
        }
      LKW; __builtin_amdgcn_sched_barrier(0);
      #pragma unroll
      for (int cl = 0; cl < 4; cl++){
        bf16x8 tf = *(const bf16x8*)&tst[w][cl*512 + lane*8];
        sacc = __builtin_amdgcn_mfma_f32_16x16x32_bf16(tf, xf[h*4 + cl], sacc, 0, 0, 0);
      }
      LKW;   // reads drained before next-half overwrite
    }

    // ---- skv[m] = X[m].ck ----
    float skv = 0.f;
    #pragma unroll
    for (int c = 0; c < 8; c++){
      bf16x8 cv = *(const bf16x8*)&ckb[c*32 + dsub];
      #pragma unroll
      for (int e = 0; e < 8; e++) skv = fmaf(bfs(xf[c][e]), bfs(cv[e]), skv);
    }
    skv += __shfl_xor(skv, 16); skv += __shfl_xor(skv, 32);

    // ---- softmax (C-layout) -> atn[w] ----
    #pragma unroll
    for (int jj = 0; jj < 4; jj++){
      int i_ = (lane >> 4)*4 + jj, j_ = lane & 15;
      bool ok = (((i_ ^ j_) & 8) == 0) &&
                ((MASK64 >> (((i_ & 7) << 3) | (j_ & 7))) & 1ull);
      float sv = ok ? (sacc[jj] + skv) : -3.0e38f;
      float mx = sv;
      mx = fmaxf(mx, __shfl_xor(mx, 1));
      mx = fmaxf(mx, __shfl_xor(mx, 2));
      mx = fmaxf(mx, __shfl_xor(mx, 4));
      float e = ok ? __expf(sv - mx) : 0.f;
      float sum = e;
      sum += __shfl_xor(sum, 1); sum += __shfl_xor(sum, 2); sum += __shfl_xor(sum, 4);
      atn[w][i_][j_] = e / sum;
    }
    LKW;   // own-wave atn writes -> reads

    // ---- PV: yfrag (A-layout) via shfl from xf ----
    bf16x8 yfrag[8];
    {
      float4 A0 = *(const float4*)&atn[w][lane & 15][lane & 8];
      float4 A1 = *(const float4*)&atn[w][lane & 15][(lane & 8) + 4];
      float am[8] = {A0.x, A0.y, A0.z, A0.w, A1.x, A1.y, A1.z, A1.w};
      #pragma unroll
      for (int c = 0; c < 8; c++){
        float a8[8] = {0,0,0,0,0,0,0,0};
        #pragma unroll
        for (int mi = 0; mi < 8; mi++){
          bf16x8 xs = shfl8(xf[c], (lane & 48) | (lane & 8) | mi);
          #pragma unroll
          for (int e = 0; e < 8; e++) a8[e] = fmaf(am[mi], bfs(xs[e]), a8[e]);
        }
        yfrag[c] = pk8(a8);
      }
    }

    // ---- stash X (A-layout, contiguous b128) -> tst[w]; xf dead until LN-apply ----
    #pragma unroll
    for (int c = 0; c < 8; c++)
      *(bf16x8*)&tst[w][c*512 + lane*8] = xf[c];
    LKW; __builtin_amdgcn_sched_barrier(0);

    // ---- GEMM2 + epilogue per half: t = acc + cvo + X_res (from stash, C-layout) ----
    float rs[4] = {0,0,0,0}, rq[4] = {0,0,0,0};
    #pragma unroll
    for (int h = 0; h < 2; h++){
      f32x4 acc[8] = {};
      #pragma unroll
      for (int kk = 0; kk < 8; kk++)
        #pragma unroll
        for (int nj = 0; nj < 8; nj++){
          bf16x8 bv = *(const bf16x8*)(Wv_ + (size_t)(kk*16 + h*8 + nj)*512 + lane*8);
          acc[nj] = __builtin_amdgcn_mfma_f32_16x16x32_bf16(yfrag[kk], bv, acc[nj], 0, 0, 0);
        }
      #pragma unroll
      for (int nj = 0; nj < 8; nj++){
        int n = h*128 + nj*16 + (lane & 15);
        float sadd = s_add[n];
        #pragma unroll
        for (int jj = 0; jj < 4; jj++){
          int i_ = (lane >> 4)*4 + jj;
          int ad = (n >> 5)*512 + (i_ + 16*((n >> 3) & 3))*8 + (n & 7);
          float t = acc[nj][jj] + sadd + bfs(tst[w][ad]);   // RAW same-lane: dep-ordered
          rs[jj] += t; rq[jj] = fmaf(t, t, rq[jj]);
          tst[w][ad] = (short)f2bf(t);                      // overwrite X slot with t
        }
      }
    }
    // ---- LN stats -> atn[w] scratch (attn probs dead) ----
    float* stp = &atn[w][0][0];
    #pragma unroll
    for (int jj = 0; jj < 4; jj++){
      float s = rs[jj], q = rq[jj];
      s += __shfl_xor(s, 1); q += __shfl_xor(q, 1);
      s += __shfl_xor(s, 2); q += __shfl_xor(q, 2);
      s += __shfl_xor(s, 4); q += __shfl_xor(q, 4);
      s += __shfl_xor(s, 8); q += __shfl_xor(q, 8);
      if ((lane & 15) == 0){
        int i_ = (lane >> 4)*4 + jj;
        float mn = s * (1.f/256.f);
        float var = q * (1.f/256.f) - mn*mn;
        stp[i_]      = mn;
        stp[16 + i_] = rsqrtf(fmaxf(var, 0.f) + 1e-5f);
      }
    }
    LKW; __builtin_amdgcn_sched_barrier(0);   // t-writes + stp visible within wave
    // ---- LN apply: read t (A-layout contiguous), row stats = row lane&15 ----
    {
      float mn = stp[lane & 15], rr = stp[16 + (lane & 15)];
      #pragma unroll
      for (int c = 0; c < 8; c++){
        bf16x8 tv = *(const bf16x8*)&tst[w][c*512 + lane*8];
        float v8[8];
        #pragma unroll
        for (int e = 0; e < 8; e++){
          int d = c*32 + dsub + e;
          v8[e] = (bfs(tv[e]) - mn) * rr * s_g[d] + s_b[d];
        }
        xf[c] = pk8(v8);
      }
    }
    LKW;   // stash reads drained before next layer reuses tst[w]
  } // layers

  // ===== head: GDP-reduce -> Astage -> GEMM vs frag-packed WpT -> LN -> GELU =====
  __syncthreads();   // tst becomes cross-wave Astage
  short* Ast = &tst[0][0];   // [16][264] bf16
  {
    int c7 = lane & 7;
    float g = (c7 == 0) ? 0.4f : (c7 == 1) ? 0.15f : (c7 == 2) ? 0.12f :
              (c7 == 3) ? 0.1f : (c7 == 4) ? 0.08f : (c7 == 5) ? 0.08f :
              (c7 == 6) ? 0.05f : 0.02f;
    #pragma unroll
    for (int c = 0; c < 8; c++){
      float v8[8];
      #pragma unroll
      for (int e = 0; e < 8; e++){
        float v = g * bfs(xf[c][e]);
        v += __shfl_xor(v, 1); v += __shfl_xor(v, 2); v += __shfl_xor(v, 4);
        v8[e] = v;
      }
      if ((lane & 7) == 0){
        int bt = w*2 + ((lane >> 3) & 1);
        *(bf16x8*)&Ast[bt*264 + dsub + 32*c] = pk8(v8);
      }
    }
  }
  __syncthreads();
  f32x4 ha[2] = {};
  #pragma unroll
  for (int kk = 0; kk < 8; kk++){
    bf16x8 av = *(const bf16x8*)&Ast[(lane & 15)*264 + kk*32 + dsub];
    #pragma unroll
    for (int nj = 0; nj < 2; nj++){
      bf16x8 bv = *(const bf16x8*)(WpT + (size_t)(kk*16 + w*2 + nj)*512 + lane*8);
      ha[nj] = __builtin_amdgcn_mfma_f32_16x16x32_bf16(av, bv, ha[nj], 0, 0, 0);
    }
  }
  #pragma unroll
  for (int jj = 0; jj < 4; jj++){
    float s = 0.f, q = 0.f;
    #pragma unroll
    for (int nj = 0; nj < 2; nj++){
      int cx = w*32 + nj*16 + (lane & 15);
      float t = ha[nj][jj] + bpv[cx];
      ha[nj][jj] = t;
      s += t; q = fmaf(t, t, q);
    }
    s += __shfl_xor(s, 1); q += __shfl_xor(q, 1);
    s += __shfl_xor(s, 2); q += __shfl_xor(q, 2);
    s += __shfl_xor(s, 4); q += __shfl_xor(q, 4);
    s += __shfl_xor(s, 8); q += __shfl_xor(q, 8);
    if ((lane & 15) == 0){
      int rl = (lane >> 4)*4 + jj;
      redS[w][rl] = s; redQ[w][rl] = q;
    }
  }
  __syncthreads();
  if (tid < 16){
    float sm = 0.f, sq = 0.f;
    #pragma unroll
    for (int w2 = 0; w2 < 8; w2++){ sm += redS[w2][tid]; sq += redQ[w2][tid]; }
    float mn = sm * (1.f/256.f);
    float var = sq * (1.f/256.f) - mn*mn;
    s_mean[tid] = mn;
    s_rstd[tid] = rsqrtf(fmaxf(var, 0.f) + 1e-5f);
  }
  __syncthreads();
  #pragma unroll
  for (int jj = 0; jj < 4; jj++){
    int rl = (lane >> 4)*4 + jj;
    float mn = s_mean[rl], rstd = s_rstd[rl];
    #pragma unroll
    for (int nj = 0; nj < 2; nj++){
      int cx = w*32 + nj*16 + (lane & 15);
      float y = (ha[nj][jj] - mn) * rstd * lpg[cx] + lpb[cx];
      outp[(size_t)(b0 + rl)*256 + cx] = 0.5f * y * (1.0f + erff(y * 0.70710678118654752f));
    }
  }
  #undef LKW
}

extern "C" void kernel_launch(void* const* d_in, const int* in_sizes, int n_in,
                              void* d_out, int out_size, void* d_ws, size_t ws_size,
                              hipStream_t stream){
  (void)in_sizes; (void)n_in; (void)out_size; (void)ws_size;
  const float* rf  = (const float*)d_in[0];
  const float* Wi  = (const float*)d_in[1];
  const float* bi  = (const float*)d_in[2];
  const float* emb = (const float*)d_in[3];
  const float* Wq  = (const float*)d_in[4];
  const float* bq  = (const float*)d_in[5];
  const float* Wk  = (const float*)d_in[6];
  const float* bk  = (const float*)d_in[7];
  const float* Wv  = (const float*)d_in[8];
  const float* bv  = (const float*)d_in[9];
  const float* Wo  = (const float*)d_in[10];
  const float* bo  = (const float*)d_in[11];
  const float* lng = (const float*)d_in[12];
  const float* lnb = (const float*)d_in[13];
  const float* Wp  = (const float*)d_in[14];
  const float* bp  = (const float*)d_in[15];
  const float* lpg = (const float*)d_in[16];
  const float* lpb = (const float*)d_in[17];

  char* ws = (char*)d_ws;
  short* Wqb  = (short*)(ws);                      // [3][256][1024] bf16
  short* Wkb  = (short*)(ws + 1572864ull);
  short* Wvb  = (short*)(ws + 3145728ull);
  short* WoTb = (short*)(ws + 4718592ull);         // [3][256][1024]
  short* WiTb = (short*)(ws + 6291456ull);         // [256][512] row-major
  short* WpTb = (short*)(ws + 6553600ull);         // [256][256] row-major
  short* Wqk  = (short*)(ws + 6684672ull);         // [3][256][256] row-major, pre-scaled 1/16
  short* Wvo  = (short*)(ws + 7077888ull);         // [3][256][256] row-major
  float* cqv  = (float*)(ws + 7471104ull);
  float* ckv  = (float*)(ws + 7474176ull);
  float* cvov = (float*)(ws + 7477248ull);
  float* c0v  = (float*)(ws + 7480320ull);
  // frag-packed copies
  short* WqkP = (short*)(ws + 7483392ull);         // [3][8][16][512]
  short* WvoP = (short*)(ws + 7876608ull);         // [3][8][16][512]
  short* WiTP = (short*)(ws + 8269824ull);         // [16][16][512]
  short* WpTP = (short*)(ws + 8531968ull);         // [8][16][512]

  { CvP cv;
    cv.src[0]=Wq; cv.dst[0]=Wqb;
    cv.src[1]=Wk; cv.dst[1]=Wkb;
    cv.src[2]=Wv; cv.dst[2]=Wvb;
    cv.src[3]=Wv; cv.dst[3]=Wvb;   // unused slot
    cv.boff[0]=0; cv.boff[1]=384; cv.boff[2]=768; cv.boff[3]=1152; cv.boff[4]=1152;
    k_convert<<<dim3(1152), dim3(256), 0, stream>>>(cv); }

  { TrP tp;
    tp.src[0]=Wi;          tp.dst[0]=WiTb;          tp.rows[0]=512;  tp.cols[0]=256;
    tp.src[1]=Wo;          tp.dst[1]=WoTb;          tp.rows[1]=1024; tp.cols[1]=256;
    tp.src[2]=Wo+262144;   tp.dst[2]=WoTb+262144;   tp.rows[2]=1024; tp.cols[2]=256;
    tp.src[3]=Wo+524288;   tp.dst[3]=WoTb+524288;   tp.rows[3]=1024; tp.cols[3]=256;
    tp.src[4]=Wp;          tp.dst[4]=WpTb;          tp.rows[4]=256;  tp.cols[4]=256;
    tp.toff[0]=0; tp.toff[1]=32; tp.toff[2]=96; tp.toff[3]=160; tp.toff[4]=224; tp.toff[5]=240;
    k_transpose<<<dim3(240), dim3(256), 0, stream>>>(tp); }

  k_vecs2<<<dim3(4, 3), dim3(256), 0, stream>>>(Wqb, Wkb, WoTb, bq, bk, bv, bo,
                                                cqv, ckv, cvov, c0v);

  { GemmP g{};
    for (int l = 0; l < 3; l++){
      g.d[l]   = GDesc{ Wkb  + l*262144, Wqb + l*262144, Wqk + l*65536, 1024, 0.0625f };
      g.d[3+l] = GDesc{ WoTb + l*262144, Wvb + l*262144, Wvo + l*65536, 1024, 1.0f };
    }
    k_gemm128<<<dim3(2,2,6), dim3(256), 0, stream>>>(g); }

  { RpP rp;
    for (int l = 0; l < 3; l++){
      rp.src[l]   = Wqk + l*65536; rp.dst[l]   = WqkP + l*65536; rp.K[l]   = 256;
      rp.src[3+l] = Wvo + l*65536; rp.dst[3+l] = WvoP + l*65536; rp.K[3+l] = 256;
    }
    rp.src[6] = WiTb; rp.dst[6] = WiTP; rp.K[6] = 512;
    rp.src[7] = WpTb; rp.dst[7] = WpTP; rp.K[7] = 256;
    rp.boff[0]=0; rp.boff[1]=8; rp.boff[2]=16; rp.boff[3]=24; rp.boff[4]=32;
    rp.boff[5]=40; rp.boff[6]=48; rp.boff[7]=64; rp.boff[8]=72;
    k_repack<<<dim3(72), dim3(256), 0, stream>>>(rp); }

  k_net<<<dim3(512), dim3(512), 0, stream>>>(rf, WiTP, bi, emb, WqkP, WvoP,
      ckv, cvov, lng, lnb, WpTP, bp, lpg, lpb, (float*)d_out);
}